// Round 10
// baseline (2199.440 us; speedup 1.0000x reference)
//
#include <hip/hip_runtime.h>
#include <hip/hip_bf16.h>
#include <cstdint>

#define DEV __device__ __forceinline__

typedef __hip_bfloat16 bf16;
typedef unsigned short u16;
typedef unsigned int u32;
typedef __attribute__((ext_vector_type(8))) short s8v;   // 8 bf16 (4 VGPRs) MFMA A/B frag
typedef __attribute__((ext_vector_type(4))) float f4;    // MFMA C/D frag

static constexpr int Bn = 128;
static constexpr int Tn = 256;
static constexpr int Dn = 384;
static constexpr int Hn = 6;
static constexpr int HDn = 64;
static constexpr int FFn = 1536;
static constexpr int Vn = 95;
static constexpr int Mn = Bn * 256;   // 32768

DEV u16 f2b(float f) {
  bf16 h = __float2bfloat16(f);
  return *reinterpret_cast<u16*>(&h);
}
DEV u32 pk2(float a, float b) { return (u32)f2b(a) | ((u32)f2b(b) << 16); }

// async 16B global->LDS. LDS destination is wave-uniform base + lane*16.
DEV void gl_lds16(const void* g, void* l) {
  auto gp = (const __attribute__((address_space(1))) u32*)(uintptr_t)g;
  auto lp = (__attribute__((address_space(3))) u32*)(u32)(uintptr_t)l;
  __builtin_amdgcn_global_load_lds(gp, lp, 16, 0, 0);
}

// counted vmcnt with literal immediate (folds under full unroll)
DEV void waitvm(int n) {
  if (n == 0)       asm volatile("s_waitcnt vmcnt(0)" ::: "memory");
  else if (n == 2)  asm volatile("s_waitcnt vmcnt(2)" ::: "memory");
  else if (n == 4)  asm volatile("s_waitcnt vmcnt(4)" ::: "memory");
  else if (n == 6)  asm volatile("s_waitcnt vmcnt(6)" ::: "memory");
  else if (n == 8)  asm volatile("s_waitcnt vmcnt(8)" ::: "memory");
  else if (n == 12) asm volatile("s_waitcnt vmcnt(12)" ::: "memory");
  else              asm volatile("s_waitcnt vmcnt(16)" ::: "memory");
}

// ---------------------------------------------------------------------------
// Hybrid GEMM — R4 single-barrier pipelined schedule (QKV / head).
// MODE 0: bf16 out [M,N]   MODE 3: f32 head out [M,95] col-guarded
// MODE 4: fused QKV: n<384 q; n<768 k; n>=768 v in vT layout [(b,h)][d][t]
// ---------------------------------------------------------------------------
template <int MODE, bool RELU, int NKT, int NT>
__global__ __launch_bounds__(256, 2) void gemm_h(
    const u16* __restrict__ A, const u16* __restrict__ Bw,
    const float* __restrict__ bias, const float* __restrict__ resid,
    void* __restrict__ outp)
{
  constexpr int K = NKT * 64;
  constexpr int N = NT * 16;
  constexpr int nTiles = NT / 8;
  __shared__ __align__(16) u16 As[3][128 * 64];
  const int tid = threadIdx.x;
  const int lane = tid & 63, wave = tid >> 6;
  const int quad = lane >> 4, l16 = lane & 15;
  const int wy = wave >> 1, wx = wave & 1;
  const int blk = blockIdx.x;
  const int xcd = blk & 7, tt = blk >> 3;
  const int nT = tt % nTiles, mT = xcd + 8 * (tt / nTiles);
  const int mBase = mT * 128, nBase = nT * 128;

  f4 acc[4][4] = {};

  int rS[4], cS[4];
#pragma unroll
  for (int i = 0; i < 4; i++) {
    int s = i * 256 + tid;
    rS[i] = s >> 3;
    cS[i] = ((s & 7) ^ (rS[i] & 7)) * 8;
  }

  const u16* Ab = A + (size_t)mBase * K;
  const u16* Bp = Bw + (size_t)((nBase >> 4) + wx * 4) * 512 + lane * 8;

#define STAGEA(buf, kt)                                                       \
  do {                                                                        \
    _Pragma("unroll")                                                         \
    for (int i = 0; i < 4; i++)                                               \
      gl_lds16(Ab + (size_t)rS[i] * K + (kt) + cS[i],                         \
               &As[buf][(i * 256 + wave * 64) * 8]);                          \
  } while (0)

  // prologue: issue order MUST be stage(0), bqa(0), stage(1)
  s8v bqa[2][4];
  STAGEA(0, 0);
  __builtin_amdgcn_sched_barrier(0);
#pragma unroll
  for (int j = 0; j < 4; j++)
    bqa[0][j] = *(const s8v*)(Bp + (size_t)0 * (NT * 512) + j * 512);
  __builtin_amdgcn_sched_barrier(0);
  STAGEA(1, 64);
  __builtin_amdgcn_sched_barrier(0);

  const int nk = NKT;
#pragma unroll
  for (int ik = 0; ik < nk; ik++) {
    const int cur = ik % 3;
    const int par = ik & 1;
    waitvm((ik + 1 < nk) ? 4 : 0);
    asm volatile("s_barrier" ::: "memory");
    s8v bqb[4];
#pragma unroll
    for (int j = 0; j < 4; j++)
      bqb[j] = *(const s8v*)(Bp + (size_t)(ik * 2 + 1) * (NT * 512) + j * 512);
    __builtin_amdgcn_sched_barrier(0);
    if (ik + 1 < nk) {
#pragma unroll
      for (int j = 0; j < 4; j++)
        bqa[par ^ 1][j] = *(const s8v*)(Bp + (size_t)(ik * 2 + 2) * (NT * 512) + j * 512);
    }
    __builtin_amdgcn_sched_barrier(0);
    if (ik + 2 < nk) STAGEA((ik + 2) % 3, (ik + 2) * 64);
    __builtin_amdgcn_sched_barrier(0);
    {
      s8v af[4];
#pragma unroll
      for (int i = 0; i < 4; i++) {
        int row = wy * 64 + i * 16 + l16;
        int ch = quad ^ (row & 7);
        af[i] = *(const s8v*)&As[cur][row * 64 + ch * 8];
      }
#pragma unroll
      for (int i = 0; i < 4; i++)
#pragma unroll
        for (int j = 0; j < 4; j++)
          acc[i][j] = __builtin_amdgcn_mfma_f32_16x16x32_bf16(af[i], bqa[par][j], acc[i][j], 0, 0, 0);
    }
    waitvm(4 * ((ik + 1 < nk) + (ik + 2 < nk)));
    {
      s8v af[4];
#pragma unroll
      for (int i = 0; i < 4; i++) {
        int row = wy * 64 + i * 16 + l16;
        int ch = (4 + quad) ^ (row & 7);
        af[i] = *(const s8v*)&As[cur][row * 64 + ch * 8];
      }
#pragma unroll
      for (int i = 0; i < 4; i++)
#pragma unroll
        for (int j = 0; j < 4; j++)
          acc[i][j] = __builtin_amdgcn_mfma_f32_16x16x32_bf16(af[i], bqb[j], acc[i][j], 0, 0, 0);
    }
  }
#undef STAGEA

  if (MODE == 0) {
    u16* out = (u16*)outp;
#pragma unroll
    for (int j = 0; j < 4; j++) {
      int n = nBase + wx * 64 + j * 16 + l16;
      float bv = bias ? bias[n] : 0.f;
#pragma unroll
      for (int i = 0; i < 4; i++) {
        int m0 = mBase + wy * 64 + i * 16 + quad * 4;
#pragma unroll
        for (int r = 0; r < 4; r++) {
          float v = acc[i][j][r] + bv;
          if (RELU) v = fmaxf(v, 0.f);
          out[(size_t)(m0 + r) * N + n] = f2b(v);
        }
      }
    }
  } else if (MODE == 3) {
    float* out = (float*)outp;
#pragma unroll
    for (int j = 0; j < 4; j++) {
      int n = nBase + wx * 64 + j * 16 + l16;
      if (n < Vn) {
        float bv = bias[n];
#pragma unroll
        for (int i = 0; i < 4; i++) {
          int m0 = mBase + wy * 64 + i * 16 + quad * 4;
#pragma unroll
          for (int r = 0; r < 4; r++)
            out[(size_t)(m0 + r) * Vn + n] = acc[i][j][r] + bv;
        }
      }
    }
  } else if (MODE == 4) {
    u16* qb = (u16*)outp;
    u16* kb = qb + (size_t)Mn * 384;
    u16* vb = kb + (size_t)Mn * 384;
#pragma unroll
    for (int j = 0; j < 4; j++) {
      int n = nBase + wx * 64 + j * 16 + l16;
      if (n < 768) {
        u16* dst = (n < 384) ? qb : kb;
        int col = (n < 384) ? n : (n - 384);   // 384 is NOT pow2 — no mask!
#pragma unroll
        for (int i = 0; i < 4; i++) {
          int m0 = mBase + wy * 64 + i * 16 + quad * 4;
#pragma unroll
          for (int r = 0; r < 4; r++)
            dst[(size_t)(m0 + r) * 384 + col] = f2b(acc[i][j][r]);
        }
      } else {
        int n7 = n - 768;
        int hh = n7 >> 6, d = n7 & 63;
#pragma unroll
        for (int i = 0; i < 4; i++) {
          int m0 = mBase + wy * 64 + i * 16 + quad * 4;
          int b = m0 >> 8, t0 = m0 & 255;
          uint2 w;
          w.x = pk2(acc[i][j][0], acc[i][j][1]);
          w.y = pk2(acc[i][j][2], acc[i][j][3]);
          *(uint2*)&vb[((b * Hn + hh) * HDn + d) * Tn + t0] = w;
        }
      }
    }
  }
}

// ---------------------------------------------------------------------------
// WO GEMM + residual-add + LayerNorm fusion (N=384 full-row tile), R6 form.
// At the mixed-rw traffic ceiling (~61us = 170MB / 2.8 TB/s) — unchanged.
// ---------------------------------------------------------------------------
template <int NKT>
__global__ __launch_bounds__(512, 2) void gemm_ln(
    const u16* __restrict__ A, const u16* __restrict__ Bw,
    const float* __restrict__ bias, const float* __restrict__ resid,
    float* __restrict__ xout,
    const float* __restrict__ sc, const float* __restrict__ bi,
    u16* __restrict__ hout)
{
  constexpr int K = NKT * 64;
  constexpr int NT = 24;               // 384 / 16
  __shared__ __align__(16) u16 As[2][128 * 64];
  __shared__ __align__(16) u16 Bs[2][24576];      // 2 ks x 24 nt x 512
  __shared__ float2 red[4][128];
  const int tid = threadIdx.x;
  const int lane = tid & 63, wave = tid >> 6;       // 0..7
  const int quad = lane >> 4, l16 = lane & 15;
  const int wy = wave >> 2, wx = wave & 3;          // 2 x 4
  const int blk = blockIdx.x;
  const int mT = (blk & 7) + 8 * (blk >> 3);        // XCD-major
  const int mBase = mT * 128;

  f4 acc[4][6] = {};

  int rS[2], cS[2];
#pragma unroll
  for (int i = 0; i < 2; i++) {
    int s = i * 512 + tid;
    rS[i] = s >> 3;
    cS[i] = ((s & 7) ^ (rS[i] & 7)) * 8;
  }

  const u16* Ab = A + (size_t)mBase * K;

#define STAGEL(buf, kt)                                                       \
  do {                                                                        \
    _Pragma("unroll")                                                         \
    for (int i = 0; i < 2; i++)                                               \
      gl_lds16(Ab + (size_t)rS[i] * K + (kt) + cS[i],                         \
               &As[buf][(i * 512 + wave * 64) * 8]);                          \
  } while (0)

#define STAGEB2(buf, ikk)                                                     \
  do {                                                                        \
    _Pragma("unroll")                                                         \
    for (int L = 0; L < 6; L++) {                                             \
      int ks = L / 3, th = L % 3;                                             \
      int c = th * 4096 + tid * 8;                                            \
      gl_lds16(Bw + (size_t)((ikk) * 2 + ks) * (NT * 512) + c,                \
               &Bs[buf][ks * 12288 + c]);                                     \
    }                                                                         \
  } while (0)

  STAGEL(0, 0);
  STAGEB2(0, 0);

  const int nk = NKT;
#pragma unroll
  for (int ik = 0; ik < nk; ik++) {
    const int cur = ik & 1;
    asm volatile("s_waitcnt vmcnt(0)" ::: "memory");
    asm volatile("s_barrier" ::: "memory");
    if (ik + 1 < nk) {
      STAGEL(cur ^ 1, (ik + 1) * 64);
      STAGEB2(cur ^ 1, ik + 1);
    }
    __builtin_amdgcn_sched_barrier(0);
#pragma unroll
    for (int ks = 0; ks < 2; ks++) {
      s8v af[4], bq[6];
#pragma unroll
      for (int i = 0; i < 4; i++) {
        int row = wy * 64 + i * 16 + l16;
        int ch = (ks * 4 + quad) ^ (row & 7);
        af[i] = *(const s8v*)&As[cur][row * 64 + ch * 8];
      }
#pragma unroll
      for (int j = 0; j < 6; j++)
        bq[j] = *(const s8v*)&Bs[cur][ks * 12288 + (wx * 6 + j) * 512 + lane * 8];
#pragma unroll
      for (int i = 0; i < 4; i++)
#pragma unroll
        for (int j = 0; j < 6; j++)
          acc[i][j] = __builtin_amdgcn_mfma_f32_16x16x32_bf16(af[i], bq[j], acc[i][j], 0, 0, 0);
    }
  }
#undef STAGEL
#undef STAGEB2

  // ---- epilogue: x = resid + C + bias; row stats; h = LN(x)*sc + bi ----
  f4 psum[4] = {}, psq[4] = {};
#pragma unroll
  for (int j = 0; j < 6; j++) {
    int n = wx * 96 + j * 16 + l16;
    float bv = bias[n];
#pragma unroll
    for (int i = 0; i < 4; i++) {
      int m0 = mBase + wy * 64 + i * 16 + quad * 4;
#pragma unroll
      for (int r = 0; r < 4; r++) {
        int m = m0 + r;
        float v = resid[(size_t)m * Dn + n] + acc[i][j][r] + bv;
        xout[(size_t)m * Dn + n] = v;
        acc[i][j][r] = v;
        psum[i][r] += v;
        psq[i][r] += v * v;
      }
    }
  }
#pragma unroll
  for (int o = 1; o < 16; o <<= 1)
#pragma unroll
    for (int i = 0; i < 4; i++)
#pragma unroll
      for (int r = 0; r < 4; r++) {
        psum[i][r] += __shfl_xor(psum[i][r], o);
        psq[i][r] += __shfl_xor(psq[i][r], o);
      }
  if (l16 == 0) {
#pragma unroll
    for (int i = 0; i < 4; i++)
#pragma unroll
      for (int r = 0; r < 4; r++) {
        int lr = wy * 64 + i * 16 + quad * 4 + r;
        float2 p; p.x = psum[i][r]; p.y = psq[i][r];
        red[wx][lr] = p;
      }
  }
  __syncthreads();
  float scv[6], biv[6];
#pragma unroll
  for (int j = 0; j < 6; j++) {
    int n = wx * 96 + j * 16 + l16;
    scv[j] = sc[n];
    biv[j] = bi[n];
  }
#pragma unroll
  for (int i = 0; i < 4; i++)
#pragma unroll
    for (int r = 0; r < 4; r++) {
      int lr = wy * 64 + i * 16 + quad * 4 + r;
      float ts = 0.f, tq = 0.f;
#pragma unroll
      for (int w = 0; w < 4; w++) { float2 p = red[w][lr]; ts += p.x; tq += p.y; }
      float mean = ts * (1.f / 384.f);
      float inv = rsqrtf(tq * (1.f / 384.f) - mean * mean + 1e-5f);
      int m = mBase + lr;
#pragma unroll
      for (int j = 0; j < 6; j++) {
        int n = wx * 96 + j * 16 + l16;
        hout[(size_t)m * Dn + n] = f2b((acc[i][j][r] - mean) * inv * scv[j] + biv[j]);
      }
    }
}

// ---------------------------------------------------------------------------
// R9 (resubmitted unchanged after infra failure): FUSED FFN v3 — R7 geometry
// (128 rows, 8 waves 2x4, 1 block/CU) with:
//  (1) NO Hs staging: h fragments read directly from global (L2-hot; tile
//      96KB/block, re-read ~1.15MB/block = 13 B/cy/CU << 56 B/cy L2 share).
//      Removes the 7.08M Hs bank conflicts and the staging barrier.
//  (2) Ps DOUBLE-buffered (2x32KB + red = 68KB) -> ONE barrier per chunk:
//      segment s = { GEMM1(s)->Ps[s&1]; GEMM2(s-1) from Ps[(s-1)&1];
//      lgkmcnt(0); barrier }. WAR safe: Ps[s&1]'s previous reader GEMM2(s-2)
//      finished before the s-1 barrier. GEMM2's LDS-fed MFMAs overlap
//      GEMM1's global latency.
// P addressing/swizzle, acc2 layout, epilogue: byte-identical to R7 (verified).
// Hang-audit (R9 post-mortem): barriers are uniform (seg guards are
// block-uniform, no barrier inside them); h in/out aliasing is per-block
// row-local with all reads before epilogue writes. No deadlock path.
// ---------------------------------------------------------------------------
__global__ __launch_bounds__(512, 2) void ffn_ln(
    const u16* __restrict__ A, const u16* __restrict__ B1w,
    const float* __restrict__ b1, const u16* __restrict__ B2w,
    const float* __restrict__ b2, const float* __restrict__ resid,
    float* __restrict__ xout,
    const float* __restrict__ sc, const float* __restrict__ bi,
    u16* __restrict__ hout)
{
  __shared__ __align__(16) u16 Ps[2][128 * 128];   // 64 KB (double-buffered)
  __shared__ float2 red[4][128];                   // 4 KB
  const int tid = threadIdx.x;
  const int lane = tid & 63, wave = tid >> 6;
  const int quad = lane >> 4, l16 = lane & 15;
  const int wy = wave >> 2, wx = wave & 3;         // 2 x 4
  const int mT = (blockIdx.x & 7) + 8 * (blockIdx.x >> 3);
  const int mBase = mT * 128;

  const u16* hg = A + (size_t)mBase * Dn;
  const u16* B1p = B1w + (size_t)(wx * 2) * 512 + lane * 8;
  const u16* B2p = B2w + (size_t)(wx * 6) * 512 + lane * 8;

  f4 acc2[4][6] = {};

#pragma unroll 1
  for (int seg = 0; seg <= 12; seg++) {
    // ---------------- GEMM1 on chunk seg: P = relu(h @ W1[:,seg*128..]+b1)
    if (seg < 12) {
      const int c = seg;
      float4 b1v0 = *(const float4*)&b1[c * 128 + wx * 32 + quad * 4];
      float4 b1v1 = *(const float4*)&b1[c * 128 + wx * 32 + 16 + quad * 4];
      f4 acc1[4][2] = {};
#pragma unroll
      for (int ik = 0; ik < 6; ik++) {
#pragma unroll
        for (int ks = 0; ks < 2; ks++) {
          s8v bq1[2], af[4];
#pragma unroll
          for (int j = 0; j < 2; j++)
            bq1[j] = *(const s8v*)(B1p + (size_t)((ik * 2 + ks) * 96 + c * 8 + j) * 512);
#pragma unroll
          for (int i = 0; i < 4; i++) {
            int row = wy * 64 + i * 16 + l16;
            af[i] = *(const s8v*)&hg[(size_t)row * Dn + ik * 64 + ks * 32 + quad * 8];
          }
#pragma unroll
          for (int i = 0; i < 4; i++)
#pragma unroll
            for (int j = 0; j < 2; j++)
              acc1[i][j] = __builtin_amdgcn_mfma_f32_16x16x32_bf16(
                  bq1[j], af[i], acc1[i][j], 0, 0, 0);
        }
      }
      // P write: bias + relu + pack; swizzled uint2 stores into Ps[c&1]
      // thread holds P(ff = c*128+wx*32+j*16+quad*4+r, m = wy*64+i*16+l16)
      char* Pb = (char*)&Ps[c & 1][0];
#pragma unroll
      for (int i = 0; i < 4; i++) {
        int m = wy * 64 + i * 16 + l16;
#pragma unroll
        for (int j = 0; j < 2; j++) {
          float4 bv4 = (j == 0) ? b1v0 : b1v1;
          float v0 = fmaxf(acc1[i][j][0] + bv4.x, 0.f);
          float v1 = fmaxf(acc1[i][j][1] + bv4.y, 0.f);
          float v2 = fmaxf(acc1[i][j][2] + bv4.z, 0.f);
          float v3 = fmaxf(acc1[i][j][3] + bv4.w, 0.f);
          uint2 w; w.x = pk2(v0, v1); w.y = pk2(v2, v3);
          int byteoff = (m * 256 + (wx * 32 + j * 16 + quad * 4) * 2) ^ ((m & 7) << 4);
          *(uint2*)(Pb + byteoff) = w;
        }
      }
    }
    // ---------------- GEMM2 on chunk seg-1: acc2 += P @ W2[cc*128.., :]
    if (seg >= 1) {
      const int cc = seg - 1;
      const char* Pb = (const char*)&Ps[cc & 1][0];
#pragma unroll
      for (int ks2 = 0; ks2 < 4; ks2++) {
        s8v bq2[6], af2[4];
#pragma unroll
        for (int j = 0; j < 6; j++)
          bq2[j] = *(const s8v*)(B2p + (size_t)((cc * 4 + ks2) * 24 + j) * 512);
#pragma unroll
        for (int i = 0; i < 4; i++) {
          int m = wy * 64 + i * 16 + l16;
          int byteoff = (m * 256 + (ks2 * 4 + quad) * 16) ^ ((m & 7) << 4);
          af2[i] = *(const s8v*)(Pb + byteoff);
        }
#pragma unroll
        for (int i = 0; i < 4; i++)
#pragma unroll
          for (int j = 0; j < 6; j++)
            acc2[i][j] = __builtin_amdgcn_mfma_f32_16x16x32_bf16(
                af2[i], bq2[j], acc2[i][j], 0, 0, 0);
      }
    }
    asm volatile("s_waitcnt lgkmcnt(0)" ::: "memory");
    asm volatile("s_barrier" ::: "memory");
  }

  // ---- epilogue: x = resid + acc2 + b2; row stats; h' = LN(x)*sc+bi ----
  f4 psum[4] = {}, psq[4] = {};
#pragma unroll
  for (int j = 0; j < 6; j++) {
    int n = wx * 96 + j * 16 + l16;
    float bv = b2[n];
#pragma unroll
    for (int i = 0; i < 4; i++) {
      int m0 = mBase + wy * 64 + i * 16 + quad * 4;
#pragma unroll
      for (int r = 0; r < 4; r++) {
        int m = m0 + r;
        float v = resid[(size_t)m * Dn + n] + acc2[i][j][r] + bv;
        xout[(size_t)m * Dn + n] = v;
        acc2[i][j][r] = v;
        psum[i][r] += v;
        psq[i][r] += v * v;
      }
    }
  }
#pragma unroll
  for (int o = 1; o < 16; o <<= 1)
#pragma unroll
    for (int i = 0; i < 4; i++)
#pragma unroll
      for (int r = 0; r < 4; r++) {
        psum[i][r] += __shfl_xor(psum[i][r], o);
        psq[i][r] += __shfl_xor(psq[i][r], o);
      }
  if (l16 == 0) {
#pragma unroll
    for (int i = 0; i < 4; i++)
#pragma unroll
      for (int r = 0; r < 4; r++) {
        int lr = wy * 64 + i * 16 + quad * 4 + r;
        float2 p; p.x = psum[i][r]; p.y = psq[i][r];
        red[wx][lr] = p;
      }
  }
  __syncthreads();
  float scv[6], biv[6];
#pragma unroll
  for (int j = 0; j < 6; j++) {
    int n = wx * 96 + j * 16 + l16;
    scv[j] = sc[n];
    biv[j] = bi[n];
  }
#pragma unroll
  for (int i = 0; i < 4; i++)
#pragma unroll
    for (int r = 0; r < 4; r++) {
      int lr = wy * 64 + i * 16 + quad * 4 + r;
      float ts = 0.f, tq = 0.f;
#pragma unroll
      for (int w = 0; w < 4; w++) { float2 p = red[w][lr]; ts += p.x; tq += p.y; }
      float mean = ts * (1.f / 384.f);
      float inv = rsqrtf(tq * (1.f / 384.f) - mean * mean + 1e-5f);
      int m = mBase + lr;
#pragma unroll
      for (int j = 0; j < 6; j++) {
        int n = wx * 96 + j * 16 + l16;
        hout[(size_t)m * Dn + n] = f2b((acc2[i][j][r] - mean) * inv * scv[j] + biv[j]);
      }
    }
}

// ---------------------------------------------------------------------------
// Flash-chunked attention v2 (unchanged).
// ---------------------------------------------------------------------------
__global__ __launch_bounds__(256) void attn_kernel(
    const u16* __restrict__ q, const u16* __restrict__ k,
    const u16* __restrict__ vT, u16* __restrict__ ao)
{
  __shared__ __align__(16) u16 Psh[4][2][16 * 40];
  const int tid = threadIdx.x, lane = tid & 63, wave = tid >> 6;
  const int quad = lane >> 4, l16 = lane & 15;
  const int c4 = blockIdx.x / 768;
  const int bh = blockIdx.x - c4 * 768;
  const int b = bh / Hn, h = bh % Hn;
  const u16* qg = q + (b * Tn) * Dn + h * HDn;
  const u16* kg = k + (b * Tn) * Dn + h * HDn;
  const u16* vg = vT + bh * (HDn * Tn);
  u16* aog = ao + (b * Tn) * Dn + h * HDn;
  const float c1 = 0.125f * 1.44269504f;  // scale * log2(e)

  const int qt = (wave & 2) ? ((wave & 1) ? 15 - c4 : 8 + c4)
                            : ((wave & 1) ? 7 - c4 : c4);
  const int qglob = qt * 16 + l16;

  const s8v qf0 = *(const s8v*)&qg[qglob * Dn + quad * 8];
  const s8v qf1 = *(const s8v*)&qg[qglob * Dn + 32 + quad * 8];

  float lsum = 0.f;
  f4 O[4] = {};

  const int nch = qt / 2 + 1;
  for (int c2 = 0; c2 < nch; c2++) {
    const int kk0 = c2 * 32;
    f4 S0 = {0.f, 0.f, 0.f, 0.f}, S1 = S0;
    {
      s8v kf = *(const s8v*)&kg[(kk0 + l16) * Dn + quad * 8];
      S0 = __builtin_amdgcn_mfma_f32_16x16x32_bf16(kf, qf0, S0, 0, 0, 0);
      kf = *(const s8v*)&kg[(kk0 + l16) * Dn + 32 + quad * 8];
      S0 = __builtin_amdgcn_mfma_f32_16x16x32_bf16(kf, qf1, S0, 0, 0, 0);
    }
    if (kk0 + 16 <= qt * 16) {
      s8v kf = *(const s8v*)&kg[(kk0 + 16 + l16) * Dn + quad * 8];
      S1 = __builtin_amdgcn_mfma_f32_16x16x32_bf16(kf, qf0, S1, 0, 0, 0);
      kf = *(const s8v*)&kg[(kk0 + 16 + l16) * Dn + 32 + quad * 8];
      S1 = __builtin_amdgcn_mfma_f32_16x16x32_bf16(kf, qf1, S1, 0, 0, 0);
    }
    const int kkq = kk0 + quad * 4;
    f4 E0, E1;
#pragma unroll
    for (int r = 0; r < 4; r++) {
      E0[r] = (kkq + r <= qglob) ? exp2f(S0[r] * c1) : 0.f;
      E1[r] = (kkq + 16 + r <= qglob) ? exp2f(S1[r] * c1) : 0.f;
      lsum += E0[r] + E1[r];
    }
    u16* prow = &Psh[wave][c2 & 1][l16 * 40];
    uint2 w0, w1;
    w0.x = pk2(E0[0], E0[1]); w0.y = pk2(E0[2], E0[3]);
    w1.x = pk2(E1[0], E1[1]); w1.y = pk2(E1[2], E1[3]);
    *(uint2*)&prow[quad * 4] = w0;
    *(uint2*)&prow[16 + quad * 4] = w1;
    const s8v pf = *(const s8v*)&prow[quad * 8];
#pragma unroll
    for (int dm = 0; dm < 4; dm++) {
      s8v vf = *(const s8v*)&vg[(dm * 16 + l16) * Tn + kk0 + quad * 8];
      O[dm] = __builtin_amdgcn_mfma_f32_16x16x32_bf16(vf, pf, O[dm], 0, 0, 0);
    }
  }

  lsum += __shfl_xor(lsum, 16);
  lsum += __shfl_xor(lsum, 32);
  const float inv = 1.0f / lsum;
#pragma unroll
  for (int dm = 0; dm < 4; dm++) {
    uint2 w;
    w.x = pk2(O[dm][0] * inv, O[dm][1] * inv);
    w.y = pk2(O[dm][2] * inv, O[dm][3] * inv);
    *(uint2*)&aog[qglob * Dn + dm * 16 + quad * 4] = w;
  }
}

// ---------------------------------------------------------------------------
// LayerNorm: one wave per token — used ONCE (after embed, layer-0 LN1).
// ---------------------------------------------------------------------------
__global__ __launch_bounds__(256) void ln_kernel(
    const float* __restrict__ x, const float* __restrict__ sc,
    const float* __restrict__ bi, u16* __restrict__ out)
{
  int tok = blockIdx.x * 4 + (threadIdx.x >> 6);
  int lane = threadIdx.x & 63;
  const float* xr = x + (size_t)tok * Dn;
  float v[6];
  float s = 0.f, sq = 0.f;
#pragma unroll
  for (int i = 0; i < 6; i++) {
    v[i] = xr[lane + 64 * i];
    s += v[i];
    sq += v[i] * v[i];
  }
#pragma unroll
  for (int o = 1; o < 64; o <<= 1) {
    s += __shfl_xor(s, o);
    sq += __shfl_xor(sq, o);
  }
  float mean = s * (1.f / 384.f);
  float var = sq * (1.f / 384.f) - mean * mean;
  float inv = rsqrtf(var + 1e-5f);
  u16* orow = out + (size_t)tok * Dn;
#pragma unroll
  for (int i = 0; i < 6; i++) {
    int c = lane + 64 * i;
    orow[c] = f2b((v[i] - mean) * inv * sc[c] + bi[c]);
  }
}

// x[m][:] = tok_emb[idx[m]][:] + pos_emb[m%T][:]  (float4 per thread)
__global__ __launch_bounds__(256) void embed_kernel(
    const int* __restrict__ idx, const float* __restrict__ tok,
    const float* __restrict__ pos, float* __restrict__ x)
{
  int i = blockIdx.x * 256 + threadIdx.x;  // [0, M*96)
  int m = i / 96, c = (i - m * 96) * 4;
  int t = m & (Tn - 1);
  const float4 tv = *(const float4*)&tok[idx[m] * Dn + c];
  const float4 pv = *(const float4*)&pos[t * Dn + c];
  float4 r;
  r.x = tv.x + pv.x; r.y = tv.y + pv.y; r.z = tv.z + pv.z; r.w = tv.w + pv.w;
  *(float4*)&x[m * Dn + c] = r;
}

// ---------------------------------------------------------------------------
// Weight converter -> MFMA B-fragment order.
// dst[((l*KC + kc)*NTtot + ntoff + nt)*512 + lane*8 + j8] = w[l][k][n] (bf16)
//   where k = kc*32 + (lane>>4)*8 + j8, n = nt*16 + (lane&15), zero if n >= C.
// ---------------------------------------------------------------------------
__global__ __launch_bounds__(256) void tcvt_frag(
    const float* __restrict__ src, u16* __restrict__ dst,
    int K, int C, int NTsub, int NTtot, int ntoff, int total)
{
  int t = blockIdx.x * 256 + threadIdx.x;
  if (t >= total) return;
  int j8 = t & 7;
  int lane = (t >> 3) & 63;
  int rest = t >> 9;
  int nt = rest % NTsub;
  int lkc = rest / NTsub;
  int KC = K >> 5;
  int kc = lkc % KC;
  int l = lkc / KC;
  int quad = lane >> 4, l16 = lane & 15;
  int k = kc * 32 + quad * 8 + j8;
  int n = nt * 16 + l16;
  float v = (n < C) ? src[((size_t)l * K + k) * C + n] : 0.f;
  dst[((size_t)(l * KC + kc) * NTtot + ntoff + nt) * 512 + lane * 8 + j8] = f2b(v);
}

extern "C" void kernel_launch(void* const* d_in, const int* in_sizes, int n_in,
                              void* d_out, int out_size, void* d_ws, size_t ws_size,
                              hipStream_t stream)
{
  (void)in_sizes; (void)n_in; (void)out_size;
  const int*   idx     = (const int*)d_in[0];
  const float* tok_emb = (const float*)d_in[1];
  const float* pos_emb = (const float*)d_in[2];
  const float* ln1_s   = (const float*)d_in[3];
  const float* ln1_b   = (const float*)d_in[4];
  const float* wq      = (const float*)d_in[5];
  const float* wk      = (const float*)d_in[6];
  const float* wv      = (const float*)d_in[7];
  const float* wo      = (const float*)d_in[8];
  const float* bo      = (const float*)d_in[9];
  const float* ln2_s   = (const float*)d_in[10];
  const float* ln2_b   = (const float*)d_in[11];
  const float* w1      = (const float*)d_in[12];
  const float* b1      = (const float*)d_in[13];
  const float* w2      = (const float*)d_in[14];
  const float* b2      = (const float*)d_in[15];
  const float* lnf_s   = (const float*)d_in[16];
  const float* lnf_b   = (const float*)d_in[17];
  const float* head_w  = (const float*)d_in[18];
  const float* head_b  = (const float*)d_in[19];
  float* out = (float*)d_out;

  // workspace layout (bytes)
  char* ws = (char*)d_ws;
  float* x  = (float*)(ws + 0);             // 50,331,648  fp32 residual stream
  u16*   h  = (u16*)(ws + 50331648);        // 25,165,824  LN output (bf16)
  u16*   qb = (u16*)(ws + 75497472);        // 25,165,824  (q,k,v contiguous!)
  u16*   kb = (u16*)(ws + 100663296);       // 25,165,824
  u16*   vb = (u16*)(ws + 125829120);       // 25,165,824  V^T [(b,h)][d][t]
  u16*   ab = (u16*)(ws + 150994944);       // 25,165,824  attn out
  u16* qkvT = (u16*)(ws + 176160768);       // 6 * 442368 (frag layout, NTtot=72)
  u16* woT  = qkvT + 6 * 442368;            // 6 * 147456 (NTtot=24)
  u16* w1T  = woT + 6 * 147456;             // 6 * 589824 (NTtot=96, K=384)
  u16* w2T  = w1T + 6 * 589824;             // 6 * 589824 (NTtot=24, K=1536)
  u16* hdT  = w2T + 6 * 589824;             // 49152 (NTtot=8, 95->128 pad)
  if (ws_size < (size_t)197492736) return;

  int tot = 6 * 384 * 384;
  tcvt_frag<<<(tot + 255) / 256, 256, 0, stream>>>(wq, qkvT, 384, 384, 24, 72, 0, tot);
  tcvt_frag<<<(tot + 255) / 256, 256, 0, stream>>>(wk, qkvT, 384, 384, 24, 72, 24, tot);
  tcvt_frag<<<(tot + 255) / 256, 256, 0, stream>>>(wv, qkvT, 384, 384, 24, 72, 48, tot);
  tcvt_frag<<<(tot + 255) / 256, 256, 0, stream>>>(wo, woT, 384, 384, 24, 24, 0, tot);
  tot = 6 * 384 * 1536;
  tcvt_frag<<<(tot + 255) / 256, 256, 0, stream>>>(w1, w1T, 384, 1536, 96, 96, 0, tot);
  tcvt_frag<<<(tot + 255) / 256, 256, 0, stream>>>(w2, w2T, 1536, 384, 24, 24, 0, tot);
  tot = 384 * 128;
  tcvt_frag<<<(tot + 255) / 256, 256, 0, stream>>>(head_w, hdT, 384, 95, 8, 8, 0, tot);

  embed_kernel<<<(Mn * 96) / 256, 256, 0, stream>>>(idx, tok_emb, pos_emb, x);
  ln_kernel<<<Mn / 4, 256, 0, stream>>>(x, ln1_s, ln1_b, h);   // layer-0 LN1

  for (int l = 0; l < 6; l++) {
    gemm_h<4, false, 6, 72><<<2304, 256, 0, stream>>>(h, qkvT + l * 442368, nullptr, nullptr, qb);
    attn_kernel<<<Bn * Hn * 4, 256, 0, stream>>>(qb, kb, vb, ab);
    // WO + residual + LN2 fused -> x, h
    gemm_ln<6><<<256, 512, 0, stream>>>(ab, woT + l * 147456, bo + l * Dn, x, x,
                                        ln2_s + l * Dn, ln2_b + l * Dn, h);
    // FFN1+relu+FFN2 + residual + LN1(next)/LNF fused -> x, h  (f1 eliminated)
    const float* ns = (l < 5) ? (ln1_s + (l + 1) * Dn) : lnf_s;
    const float* nb = (l < 5) ? (ln1_b + (l + 1) * Dn) : lnf_b;
    ffn_ln<<<256, 512, 0, stream>>>(h, w1T + l * 589824, b1 + l * FFn,
                                    w2T + l * 589824, b2 + l * Dn,
                                    x, x, ns, nb, h);
  }
  gemm_h<3, false, 6, 8><<<256, 256, 0, stream>>>(h, hdT, head_b, nullptr, out);
}

// Round 11
// 1565.965 us; speedup vs baseline: 1.4045x; 1.4045x over previous
//
#include <hip/hip_runtime.h>
#include <hip/hip_bf16.h>
#include <cstdint>

#define DEV __device__ __forceinline__

typedef __hip_bfloat16 bf16;
typedef unsigned short u16;
typedef unsigned int u32;
typedef __attribute__((ext_vector_type(8))) short s8v;   // 8 bf16 (4 VGPRs) MFMA A/B frag
typedef __attribute__((ext_vector_type(4))) float f4;    // MFMA C/D frag

static constexpr int Bn = 128;
static constexpr int Tn = 256;
static constexpr int Dn = 384;
static constexpr int Hn = 6;
static constexpr int HDn = 64;
static constexpr int FFn = 1536;
static constexpr int Vn = 95;
static constexpr int Mn = Bn * 256;   // 32768

DEV u16 f2b(float f) {
  bf16 h = __float2bfloat16(f);
  return *reinterpret_cast<u16*>(&h);
}
DEV u32 pk2(float a, float b) { return (u32)f2b(a) | ((u32)f2b(b) << 16); }

// async 16B global->LDS. LDS destination is wave-uniform base + lane*16.
DEV void gl_lds16(const void* g, void* l) {
  auto gp = (const __attribute__((address_space(1))) u32*)(uintptr_t)g;
  auto lp = (__attribute__((address_space(3))) u32*)(u32)(uintptr_t)l;
  __builtin_amdgcn_global_load_lds(gp, lp, 16, 0, 0);
}

// counted vmcnt with literal immediate (folds under full unroll)
DEV void waitvm(int n) {
  if (n == 0)       asm volatile("s_waitcnt vmcnt(0)" ::: "memory");
  else if (n == 2)  asm volatile("s_waitcnt vmcnt(2)" ::: "memory");
  else if (n == 4)  asm volatile("s_waitcnt vmcnt(4)" ::: "memory");
  else if (n == 6)  asm volatile("s_waitcnt vmcnt(6)" ::: "memory");
  else if (n == 8)  asm volatile("s_waitcnt vmcnt(8)" ::: "memory");
  else if (n == 12) asm volatile("s_waitcnt vmcnt(12)" ::: "memory");
  else              asm volatile("s_waitcnt vmcnt(16)" ::: "memory");
}

// ---------------------------------------------------------------------------
// Hybrid GEMM — R4 single-barrier pipelined schedule (QKV / head).
// MODE 0: bf16 out [M,N]   MODE 3: f32 head out [M,95] col-guarded
// MODE 4: fused QKV: n<384 q; n<768 k; n>=768 v in vT layout [(b,h)][d][t]
// ---------------------------------------------------------------------------
template <int MODE, bool RELU, int NKT, int NT>
__global__ __launch_bounds__(256, 2) void gemm_h(
    const u16* __restrict__ A, const u16* __restrict__ Bw,
    const float* __restrict__ bias, const float* __restrict__ resid,
    void* __restrict__ outp)
{
  constexpr int K = NKT * 64;
  constexpr int N = NT * 16;
  constexpr int nTiles = NT / 8;
  __shared__ __align__(16) u16 As[3][128 * 64];
  const int tid = threadIdx.x;
  const int lane = tid & 63, wave = tid >> 6;
  const int quad = lane >> 4, l16 = lane & 15;
  const int wy = wave >> 1, wx = wave & 1;
  const int blk = blockIdx.x;
  const int xcd = blk & 7, tt = blk >> 3;
  const int nT = tt % nTiles, mT = xcd + 8 * (tt / nTiles);
  const int mBase = mT * 128, nBase = nT * 128;

  f4 acc[4][4] = {};

  int rS[4], cS[4];
#pragma unroll
  for (int i = 0; i < 4; i++) {
    int s = i * 256 + tid;
    rS[i] = s >> 3;
    cS[i] = ((s & 7) ^ (rS[i] & 7)) * 8;
  }

  const u16* Ab = A + (size_t)mBase * K;
  const u16* Bp = Bw + (size_t)((nBase >> 4) + wx * 4) * 512 + lane * 8;

#define STAGEA(buf, kt)                                                       \
  do {                                                                        \
    _Pragma("unroll")                                                         \
    for (int i = 0; i < 4; i++)                                               \
      gl_lds16(Ab + (size_t)rS[i] * K + (kt) + cS[i],                         \
               &As[buf][(i * 256 + wave * 64) * 8]);                          \
  } while (0)

  // prologue: issue order MUST be stage(0), bqa(0), stage(1)
  s8v bqa[2][4];
  STAGEA(0, 0);
  __builtin_amdgcn_sched_barrier(0);
#pragma unroll
  for (int j = 0; j < 4; j++)
    bqa[0][j] = *(const s8v*)(Bp + (size_t)0 * (NT * 512) + j * 512);
  __builtin_amdgcn_sched_barrier(0);
  STAGEA(1, 64);
  __builtin_amdgcn_sched_barrier(0);

  const int nk = NKT;
#pragma unroll
  for (int ik = 0; ik < nk; ik++) {
    const int cur = ik % 3;
    const int par = ik & 1;
    waitvm((ik + 1 < nk) ? 4 : 0);
    asm volatile("s_barrier" ::: "memory");
    s8v bqb[4];
#pragma unroll
    for (int j = 0; j < 4; j++)
      bqb[j] = *(const s8v*)(Bp + (size_t)(ik * 2 + 1) * (NT * 512) + j * 512);
    __builtin_amdgcn_sched_barrier(0);
    if (ik + 1 < nk) {
#pragma unroll
      for (int j = 0; j < 4; j++)
        bqa[par ^ 1][j] = *(const s8v*)(Bp + (size_t)(ik * 2 + 2) * (NT * 512) + j * 512);
    }
    __builtin_amdgcn_sched_barrier(0);
    if (ik + 2 < nk) STAGEA((ik + 2) % 3, (ik + 2) * 64);
    __builtin_amdgcn_sched_barrier(0);
    {
      s8v af[4];
#pragma unroll
      for (int i = 0; i < 4; i++) {
        int row = wy * 64 + i * 16 + l16;
        int ch = quad ^ (row & 7);
        af[i] = *(const s8v*)&As[cur][row * 64 + ch * 8];
      }
#pragma unroll
      for (int i = 0; i < 4; i++)
#pragma unroll
        for (int j = 0; j < 4; j++)
          acc[i][j] = __builtin_amdgcn_mfma_f32_16x16x32_bf16(af[i], bqa[par][j], acc[i][j], 0, 0, 0);
    }
    waitvm(4 * ((ik + 1 < nk) + (ik + 2 < nk)));
    {
      s8v af[4];
#pragma unroll
      for (int i = 0; i < 4; i++) {
        int row = wy * 64 + i * 16 + l16;
        int ch = (4 + quad) ^ (row & 7);
        af[i] = *(const s8v*)&As[cur][row * 64 + ch * 8];
      }
#pragma unroll
      for (int i = 0; i < 4; i++)
#pragma unroll
        for (int j = 0; j < 4; j++)
          acc[i][j] = __builtin_amdgcn_mfma_f32_16x16x32_bf16(af[i], bqb[j], acc[i][j], 0, 0, 0);
    }
  }
#undef STAGEA

  if (MODE == 0) {
    u16* out = (u16*)outp;
#pragma unroll
    for (int j = 0; j < 4; j++) {
      int n = nBase + wx * 64 + j * 16 + l16;
      float bv = bias ? bias[n] : 0.f;
#pragma unroll
      for (int i = 0; i < 4; i++) {
        int m0 = mBase + wy * 64 + i * 16 + quad * 4;
#pragma unroll
        for (int r = 0; r < 4; r++) {
          float v = acc[i][j][r] + bv;
          if (RELU) v = fmaxf(v, 0.f);
          out[(size_t)(m0 + r) * N + n] = f2b(v);
        }
      }
    }
  } else if (MODE == 3) {
    float* out = (float*)outp;
#pragma unroll
    for (int j = 0; j < 4; j++) {
      int n = nBase + wx * 64 + j * 16 + l16;
      if (n < Vn) {
        float bv = bias[n];
#pragma unroll
        for (int i = 0; i < 4; i++) {
          int m0 = mBase + wy * 64 + i * 16 + quad * 4;
#pragma unroll
          for (int r = 0; r < 4; r++)
            out[(size_t)(m0 + r) * Vn + n] = acc[i][j][r] + bv;
        }
      }
    }
  } else if (MODE == 4) {
    u16* qb = (u16*)outp;
    u16* kb = qb + (size_t)Mn * 384;
    u16* vb = kb + (size_t)Mn * 384;
#pragma unroll
    for (int j = 0; j < 4; j++) {
      int n = nBase + wx * 64 + j * 16 + l16;
      if (n < 768) {
        u16* dst = (n < 384) ? qb : kb;
        int col = (n < 384) ? n : (n - 384);   // 384 is NOT pow2 — no mask!
#pragma unroll
        for (int i = 0; i < 4; i++) {
          int m0 = mBase + wy * 64 + i * 16 + quad * 4;
#pragma unroll
          for (int r = 0; r < 4; r++)
            dst[(size_t)(m0 + r) * 384 + col] = f2b(acc[i][j][r]);
        }
      } else {
        int n7 = n - 768;
        int hh = n7 >> 6, d = n7 & 63;
#pragma unroll
        for (int i = 0; i < 4; i++) {
          int m0 = mBase + wy * 64 + i * 16 + quad * 4;
          int b = m0 >> 8, t0 = m0 & 255;
          uint2 w;
          w.x = pk2(acc[i][j][0], acc[i][j][1]);
          w.y = pk2(acc[i][j][2], acc[i][j][3]);
          *(uint2*)&vb[((b * Hn + hh) * HDn + d) * Tn + t0] = w;
        }
      }
    }
  }
}

// ---------------------------------------------------------------------------
// WO GEMM + residual-add + LayerNorm fusion (N=384 full-row tile), R6 form.
// At the mixed-rw traffic ceiling (~61us = 170MB / 2.8 TB/s) — unchanged.
// ---------------------------------------------------------------------------
template <int NKT>
__global__ __launch_bounds__(512, 2) void gemm_ln(
    const u16* __restrict__ A, const u16* __restrict__ Bw,
    const float* __restrict__ bias, const float* __restrict__ resid,
    float* __restrict__ xout,
    const float* __restrict__ sc, const float* __restrict__ bi,
    u16* __restrict__ hout)
{
  constexpr int K = NKT * 64;
  constexpr int NT = 24;               // 384 / 16
  __shared__ __align__(16) u16 As[2][128 * 64];
  __shared__ __align__(16) u16 Bs[2][24576];      // 2 ks x 24 nt x 512
  __shared__ float2 red[4][128];
  const int tid = threadIdx.x;
  const int lane = tid & 63, wave = tid >> 6;       // 0..7
  const int quad = lane >> 4, l16 = lane & 15;
  const int wy = wave >> 2, wx = wave & 3;          // 2 x 4
  const int blk = blockIdx.x;
  const int mT = (blk & 7) + 8 * (blk >> 3);        // XCD-major
  const int mBase = mT * 128;

  f4 acc[4][6] = {};

  int rS[2], cS[2];
#pragma unroll
  for (int i = 0; i < 2; i++) {
    int s = i * 512 + tid;
    rS[i] = s >> 3;
    cS[i] = ((s & 7) ^ (rS[i] & 7)) * 8;
  }

  const u16* Ab = A + (size_t)mBase * K;

#define STAGEL(buf, kt)                                                       \
  do {                                                                        \
    _Pragma("unroll")                                                         \
    for (int i = 0; i < 2; i++)                                               \
      gl_lds16(Ab + (size_t)rS[i] * K + (kt) + cS[i],                         \
               &As[buf][(i * 512 + wave * 64) * 8]);                          \
  } while (0)

#define STAGEB2(buf, ikk)                                                     \
  do {                                                                        \
    _Pragma("unroll")                                                         \
    for (int L = 0; L < 6; L++) {                                             \
      int ks = L / 3, th = L % 3;                                             \
      int c = th * 4096 + tid * 8;                                            \
      gl_lds16(Bw + (size_t)((ikk) * 2 + ks) * (NT * 512) + c,                \
               &Bs[buf][ks * 12288 + c]);                                     \
    }                                                                         \
  } while (0)

  STAGEL(0, 0);
  STAGEB2(0, 0);

  const int nk = NKT;
#pragma unroll
  for (int ik = 0; ik < nk; ik++) {
    const int cur = ik & 1;
    asm volatile("s_waitcnt vmcnt(0)" ::: "memory");
    asm volatile("s_barrier" ::: "memory");
    if (ik + 1 < nk) {
      STAGEL(cur ^ 1, (ik + 1) * 64);
      STAGEB2(cur ^ 1, ik + 1);
    }
    __builtin_amdgcn_sched_barrier(0);
#pragma unroll
    for (int ks = 0; ks < 2; ks++) {
      s8v af[4], bq[6];
#pragma unroll
      for (int i = 0; i < 4; i++) {
        int row = wy * 64 + i * 16 + l16;
        int ch = (ks * 4 + quad) ^ (row & 7);
        af[i] = *(const s8v*)&As[cur][row * 64 + ch * 8];
      }
#pragma unroll
      for (int j = 0; j < 6; j++)
        bq[j] = *(const s8v*)&Bs[cur][ks * 12288 + (wx * 6 + j) * 512 + lane * 8];
#pragma unroll
      for (int i = 0; i < 4; i++)
#pragma unroll
        for (int j = 0; j < 6; j++)
          acc[i][j] = __builtin_amdgcn_mfma_f32_16x16x32_bf16(af[i], bq[j], acc[i][j], 0, 0, 0);
    }
  }
#undef STAGEL
#undef STAGEB2

  // ---- epilogue: x = resid + C + bias; row stats; h = LN(x)*sc + bi ----
  f4 psum[4] = {}, psq[4] = {};
#pragma unroll
  for (int j = 0; j < 6; j++) {
    int n = wx * 96 + j * 16 + l16;
    float bv = bias[n];
#pragma unroll
    for (int i = 0; i < 4; i++) {
      int m0 = mBase + wy * 64 + i * 16 + quad * 4;
#pragma unroll
      for (int r = 0; r < 4; r++) {
        int m = m0 + r;
        float v = resid[(size_t)m * Dn + n] + acc[i][j][r] + bv;
        xout[(size_t)m * Dn + n] = v;
        acc[i][j][r] = v;
        psum[i][r] += v;
        psq[i][r] += v * v;
      }
    }
  }
#pragma unroll
  for (int o = 1; o < 16; o <<= 1)
#pragma unroll
    for (int i = 0; i < 4; i++)
#pragma unroll
      for (int r = 0; r < 4; r++) {
        psum[i][r] += __shfl_xor(psum[i][r], o);
        psq[i][r] += __shfl_xor(psq[i][r], o);
      }
  if (l16 == 0) {
#pragma unroll
    for (int i = 0; i < 4; i++)
#pragma unroll
      for (int r = 0; r < 4; r++) {
        int lr = wy * 64 + i * 16 + quad * 4 + r;
        float2 p; p.x = psum[i][r]; p.y = psq[i][r];
        red[wx][lr] = p;
      }
  }
  __syncthreads();
  float scv[6], biv[6];
#pragma unroll
  for (int j = 0; j < 6; j++) {
    int n = wx * 96 + j * 16 + l16;
    scv[j] = sc[n];
    biv[j] = bi[n];
  }
#pragma unroll
  for (int i = 0; i < 4; i++)
#pragma unroll
    for (int r = 0; r < 4; r++) {
      int lr = wy * 64 + i * 16 + quad * 4 + r;
      float ts = 0.f, tq = 0.f;
#pragma unroll
      for (int w = 0; w < 4; w++) { float2 p = red[w][lr]; ts += p.x; tq += p.y; }
      float mean = ts * (1.f / 384.f);
      float inv = rsqrtf(tq * (1.f / 384.f) - mean * mean + 1e-5f);
      int m = mBase + lr;
#pragma unroll
      for (int j = 0; j < 6; j++) {
        int n = wx * 96 + j * 16 + l16;
        hout[(size_t)m * Dn + n] = f2b((acc[i][j][r] - mean) * inv * scv[j] + biv[j]);
      }
    }
}

// ---------------------------------------------------------------------------
// R11: FUSED FFN v4 — R7 geometry + conflict-free Hs + 1-barrier seg-loop.
// R10 verdict: direct-global-h thrashed per-XCD L2 (32 blk x 96KB h + W1/W2
// streams > 4MB) -> FETCH +78MB, 225us. Hs staging restored. Fixes vs R7:
//  (1) Hs stored as 6 As-STYLE SUBTILES [128][64] (128B row stride + XOR) —
//      byte-isomorphic to gemm_h's As reads which measure ZERO bank
//      conflicts (R7's single [128][384] tile, 768B stride, cost 7.08M
//      conflict-cycles = ~11us despite identical mod-32 bank math).
//  (2) Ps DOUBLE-buffered, ONE barrier per chunk (R10's verified seg-loop):
//      seg s: { GEMM1(s)->Ps[s&1]; GEMM2(s-1) reads Ps[(s-1)&1];
//      lgkmcnt(0); barrier }. WAR: Ps[s&1]'s prior reader GEMM2(s-2)
//      finished before barrier s-1.
// LDS = Hs 96K + Ps 64K = 160KB exactly; red (4KB) ALIASES Ps[0] (first
// touched after the final seg barrier, when all Ps reads are done).
// ---------------------------------------------------------------------------
__global__ __launch_bounds__(512, 2) void ffn_ln(
    const u16* __restrict__ A, const u16* __restrict__ B1w,
    const float* __restrict__ b1, const u16* __restrict__ B2w,
    const float* __restrict__ b2, const float* __restrict__ resid,
    float* __restrict__ xout,
    const float* __restrict__ sc, const float* __restrict__ bi,
    u16* __restrict__ hout)
{
  __shared__ __align__(16) u16 LDSu[81920];   // 160 KB total
  u16* Hs  = LDSu;            // 6 subtiles x [128][64] = 49152 u16 (96 KB)
  u16* Ps0 = LDSu + 49152;    // 16384 u16 (32 KB)
  u16* Ps1 = LDSu + 65536;    // 16384 u16 (32 KB)
  const int tid = threadIdx.x;
  const int lane = tid & 63, wave = tid >> 6;
  const int quad = lane >> 4, l16 = lane & 15;
  const int wy = wave >> 2, wx = wave & 3;         // 2 x 4
  const int mT = (blockIdx.x & 7) + 8 * (blockIdx.x >> 3);
  const int mBase = mT * 128;

  const u16* hg = A + (size_t)mBase * Dn;

  // ---- stage Hs: 12 rounds x 512 thr x 16B. 16B-slot S: ik=S>>10,
  // s_in=S&1023, row=s_in>>3, LDS chunk-slot c=s_in&7 holds source chunk
  // c^(row&7) of the ik-th 64-col group (XOR involution, As-identical). ----
#pragma unroll
  for (int i = 0; i < 12; i++) {
    u32 S = i * 512 + tid;
    u32 ik = S >> 10, s_in = S & 1023;
    u32 row = s_in >> 3, c = s_in & 7;
    u32 src = ik * 64 + (c ^ (row & 7)) * 8;
    gl_lds16(hg + (size_t)row * Dn + src, &Hs[S * 8]);
  }
  asm volatile("s_waitcnt vmcnt(0)" ::: "memory");
  asm volatile("s_barrier" ::: "memory");

  const u16* B1p = B1w + (size_t)(wx * 2) * 512 + lane * 8;
  const u16* B2p = B2w + (size_t)(wx * 6) * 512 + lane * 8;

  f4 acc2[4][6] = {};

#pragma unroll 1
  for (int seg = 0; seg <= 12; seg++) {
    // ---------------- GEMM1 on chunk seg: P = relu(h @ W1[:,seg*128..]+b1)
    if (seg < 12) {
      const int c = seg;
      float4 b1v0 = *(const float4*)&b1[c * 128 + wx * 32 + quad * 4];
      float4 b1v1 = *(const float4*)&b1[c * 128 + wx * 32 + 16 + quad * 4];
      f4 acc1[4][2] = {};
#pragma unroll
      for (int ik = 0; ik < 6; ik++) {
#pragma unroll
        for (int ks = 0; ks < 2; ks++) {
          s8v bq1[2], af[4];
#pragma unroll
          for (int j = 0; j < 2; j++)
            bq1[j] = *(const s8v*)(B1p + (size_t)((ik * 2 + ks) * 96 + c * 8 + j) * 512);
#pragma unroll
          for (int i = 0; i < 4; i++) {
            int row = wy * 64 + i * 16 + l16;
            int chx = (ks * 4 + quad) ^ (row & 7);
            af[i] = *(const s8v*)&Hs[ik * 8192 + row * 64 + chx * 8];
          }
#pragma unroll
          for (int i = 0; i < 4; i++)
#pragma unroll
            for (int j = 0; j < 2; j++)
              acc1[i][j] = __builtin_amdgcn_mfma_f32_16x16x32_bf16(
                  bq1[j], af[i], acc1[i][j], 0, 0, 0);
        }
      }
      // P write: bias + relu + pack; swizzled uint2 stores into Ps[c&1]
      // thread holds P(ff = c*128+wx*32+j*16+quad*4+r, m = wy*64+i*16+l16)
      char* Pb = (char*)((c & 1) ? Ps1 : Ps0);
#pragma unroll
      for (int i = 0; i < 4; i++) {
        int m = wy * 64 + i * 16 + l16;
#pragma unroll
        for (int j = 0; j < 2; j++) {
          float4 bv4 = (j == 0) ? b1v0 : b1v1;
          float v0 = fmaxf(acc1[i][j][0] + bv4.x, 0.f);
          float v1 = fmaxf(acc1[i][j][1] + bv4.y, 0.f);
          float v2 = fmaxf(acc1[i][j][2] + bv4.z, 0.f);
          float v3 = fmaxf(acc1[i][j][3] + bv4.w, 0.f);
          uint2 w; w.x = pk2(v0, v1); w.y = pk2(v2, v3);
          int byteoff = (m * 256 + (wx * 32 + j * 16 + quad * 4) * 2) ^ ((m & 7) << 4);
          *(uint2*)(Pb + byteoff) = w;
        }
      }
    }
    // ---------------- GEMM2 on chunk seg-1: acc2 += P @ W2[cc*128.., :]
    if (seg >= 1) {
      const int cc = seg - 1;
      const char* Pb = (const char*)((cc & 1) ? Ps1 : Ps0);
#pragma unroll
      for (int ks2 = 0; ks2 < 4; ks2++) {
        s8v bq2[6], af2[4];
#pragma unroll
        for (int j = 0; j < 6; j++)
          bq2[j] = *(const s8v*)(B2p + (size_t)((cc * 4 + ks2) * 24 + j) * 512);
#pragma unroll
        for (int i = 0; i < 4; i++) {
          int m = wy * 64 + i * 16 + l16;
          int byteoff = (m * 256 + (ks2 * 4 + quad) * 16) ^ ((m & 7) << 4);
          af2[i] = *(const s8v*)(Pb + byteoff);
        }
#pragma unroll
        for (int i = 0; i < 4; i++)
#pragma unroll
          for (int j = 0; j < 6; j++)
            acc2[i][j] = __builtin_amdgcn_mfma_f32_16x16x32_bf16(
                af2[i], bq2[j], acc2[i][j], 0, 0, 0);
      }
    }
    asm volatile("s_waitcnt lgkmcnt(0)" ::: "memory");
    asm volatile("s_barrier" ::: "memory");
  }

  // ---- epilogue: x = resid + acc2 + b2; row stats; h' = LN(x)*sc+bi ----
  // red aliases Ps0 (all Ps reads completed before the final seg barrier).
  float2* red = (float2*)Ps0;   // red[wx*128 + lr]
  f4 psum[4] = {}, psq[4] = {};
#pragma unroll
  for (int j = 0; j < 6; j++) {
    int n = wx * 96 + j * 16 + l16;
    float bv = b2[n];
#pragma unroll
    for (int i = 0; i < 4; i++) {
      int m0 = mBase + wy * 64 + i * 16 + quad * 4;
#pragma unroll
      for (int r = 0; r < 4; r++) {
        int m = m0 + r;
        float v = resid[(size_t)m * Dn + n] + acc2[i][j][r] + bv;
        xout[(size_t)m * Dn + n] = v;
        acc2[i][j][r] = v;
        psum[i][r] += v;
        psq[i][r] += v * v;
      }
    }
  }
#pragma unroll
  for (int o = 1; o < 16; o <<= 1)
#pragma unroll
    for (int i = 0; i < 4; i++)
#pragma unroll
      for (int r = 0; r < 4; r++) {
        psum[i][r] += __shfl_xor(psum[i][r], o);
        psq[i][r] += __shfl_xor(psq[i][r], o);
      }
  if (l16 == 0) {
#pragma unroll
    for (int i = 0; i < 4; i++)
#pragma unroll
      for (int r = 0; r < 4; r++) {
        int lr = wy * 64 + i * 16 + quad * 4 + r;
        float2 p; p.x = psum[i][r]; p.y = psq[i][r];
        red[wx * 128 + lr] = p;
      }
  }
  __syncthreads();
  float scv[6], biv[6];
#pragma unroll
  for (int j = 0; j < 6; j++) {
    int n = wx * 96 + j * 16 + l16;
    scv[j] = sc[n];
    biv[j] = bi[n];
  }
#pragma unroll
  for (int i = 0; i < 4; i++)
#pragma unroll
    for (int r = 0; r < 4; r++) {
      int lr = wy * 64 + i * 16 + quad * 4 + r;
      float ts = 0.f, tq = 0.f;
#pragma unroll
      for (int w = 0; w < 4; w++) { float2 p = red[w * 128 + lr]; ts += p.x; tq += p.y; }
      float mean = ts * (1.f / 384.f);
      float inv = rsqrtf(tq * (1.f / 384.f) - mean * mean + 1e-5f);
      int m = mBase + lr;
#pragma unroll
      for (int j = 0; j < 6; j++) {
        int n = wx * 96 + j * 16 + l16;
        hout[(size_t)m * Dn + n] = f2b((acc2[i][j][r] - mean) * inv * scv[j] + biv[j]);
      }
    }
}

// ---------------------------------------------------------------------------
// Flash-chunked attention v2 (unchanged).
// ---------------------------------------------------------------------------
__global__ __launch_bounds__(256) void attn_kernel(
    const u16* __restrict__ q, const u16* __restrict__ k,
    const u16* __restrict__ vT, u16* __restrict__ ao)
{
  __shared__ __align__(16) u16 Psh[4][2][16 * 40];
  const int tid = threadIdx.x, lane = tid & 63, wave = tid >> 6;
  const int quad = lane >> 4, l16 = lane & 15;
  const int c4 = blockIdx.x / 768;
  const int bh = blockIdx.x - c4 * 768;
  const int b = bh / Hn, h = bh % Hn;
  const u16* qg = q + (b * Tn) * Dn + h * HDn;
  const u16* kg = k + (b * Tn) * Dn + h * HDn;
  const u16* vg = vT + bh * (HDn * Tn);
  u16* aog = ao + (b * Tn) * Dn + h * HDn;
  const float c1 = 0.125f * 1.44269504f;  // scale * log2(e)

  const int qt = (wave & 2) ? ((wave & 1) ? 15 - c4 : 8 + c4)
                            : ((wave & 1) ? 7 - c4 : c4);
  const int qglob = qt * 16 + l16;

  const s8v qf0 = *(const s8v*)&qg[qglob * Dn + quad * 8];
  const s8v qf1 = *(const s8v*)&qg[qglob * Dn + 32 + quad * 8];

  float lsum = 0.f;
  f4 O[4] = {};

  const int nch = qt / 2 + 1;
  for (int c2 = 0; c2 < nch; c2++) {
    const int kk0 = c2 * 32;
    f4 S0 = {0.f, 0.f, 0.f, 0.f}, S1 = S0;
    {
      s8v kf = *(const s8v*)&kg[(kk0 + l16) * Dn + quad * 8];
      S0 = __builtin_amdgcn_mfma_f32_16x16x32_bf16(kf, qf0, S0, 0, 0, 0);
      kf = *(const s8v*)&kg[(kk0 + l16) * Dn + 32 + quad * 8];
      S0 = __builtin_amdgcn_mfma_f32_16x16x32_bf16(kf, qf1, S0, 0, 0, 0);
    }
    if (kk0 + 16 <= qt * 16) {
      s8v kf = *(const s8v*)&kg[(kk0 + 16 + l16) * Dn + quad * 8];
      S1 = __builtin_amdgcn_mfma_f32_16x16x32_bf16(kf, qf0, S1, 0, 0, 0);
      kf = *(const s8v*)&kg[(kk0 + 16 + l16) * Dn + 32 + quad * 8];
      S1 = __builtin_amdgcn_mfma_f32_16x16x32_bf16(kf, qf1, S1, 0, 0, 0);
    }
    const int kkq = kk0 + quad * 4;
    f4 E0, E1;
#pragma unroll
    for (int r = 0; r < 4; r++) {
      E0[r] = (kkq + r <= qglob) ? exp2f(S0[r] * c1) : 0.f;
      E1[r] = (kkq + 16 + r <= qglob) ? exp2f(S1[r] * c1) : 0.f;
      lsum += E0[r] + E1[r];
    }
    u16* prow = &Psh[wave][c2 & 1][l16 * 40];
    uint2 w0, w1;
    w0.x = pk2(E0[0], E0[1]); w0.y = pk2(E0[2], E0[3]);
    w1.x = pk2(E1[0], E1[1]); w1.y = pk2(E1[2], E1[3]);
    *(uint2*)&prow[quad * 4] = w0;
    *(uint2*)&prow[16 + quad * 4] = w1;
    const s8v pf = *(const s8v*)&prow[quad * 8];
#pragma unroll
    for (int dm = 0; dm < 4; dm++) {
      s8v vf = *(const s8v*)&vg[(dm * 16 + l16) * Tn + kk0 + quad * 8];
      O[dm] = __builtin_amdgcn_mfma_f32_16x16x32_bf16(vf, pf, O[dm], 0, 0, 0);
    }
  }

  lsum += __shfl_xor(lsum, 16);
  lsum += __shfl_xor(lsum, 32);
  const float inv = 1.0f / lsum;
#pragma unroll
  for (int dm = 0; dm < 4; dm++) {
    uint2 w;
    w.x = pk2(O[dm][0] * inv, O[dm][1] * inv);
    w.y = pk2(O[dm][2] * inv, O[dm][3] * inv);
    *(uint2*)&aog[qglob * Dn + dm * 16 + quad * 4] = w;
  }
}

// ---------------------------------------------------------------------------
// LayerNorm: one wave per token — used ONCE (after embed, layer-0 LN1).
// ---------------------------------------------------------------------------
__global__ __launch_bounds__(256) void ln_kernel(
    const float* __restrict__ x, const float* __restrict__ sc,
    const float* __restrict__ bi, u16* __restrict__ out)
{
  int tok = blockIdx.x * 4 + (threadIdx.x >> 6);
  int lane = threadIdx.x & 63;
  const float* xr = x + (size_t)tok * Dn;
  float v[6];
  float s = 0.f, sq = 0.f;
#pragma unroll
  for (int i = 0; i < 6; i++) {
    v[i] = xr[lane + 64 * i];
    s += v[i];
    sq += v[i] * v[i];
  }
#pragma unroll
  for (int o = 1; o < 64; o <<= 1) {
    s += __shfl_xor(s, o);
    sq += __shfl_xor(sq, o);
  }
  float mean = s * (1.f / 384.f);
  float var = sq * (1.f / 384.f) - mean * mean;
  float inv = rsqrtf(var + 1e-5f);
  u16* orow = out + (size_t)tok * Dn;
#pragma unroll
  for (int i = 0; i < 6; i++) {
    int c = lane + 64 * i;
    orow[c] = f2b((v[i] - mean) * inv * sc[c] + bi[c]);
  }
}

// x[m][:] = tok_emb[idx[m]][:] + pos_emb[m%T][:]  (float4 per thread)
__global__ __launch_bounds__(256) void embed_kernel(
    const int* __restrict__ idx, const float* __restrict__ tok,
    const float* __restrict__ pos, float* __restrict__ x)
{
  int i = blockIdx.x * 256 + threadIdx.x;  // [0, M*96)
  int m = i / 96, c = (i - m * 96) * 4;
  int t = m & (Tn - 1);
  const float4 tv = *(const float4*)&tok[idx[m] * Dn + c];
  const float4 pv = *(const float4*)&pos[t * Dn + c];
  float4 r;
  r.x = tv.x + pv.x; r.y = tv.y + pv.y; r.z = tv.z + pv.z; r.w = tv.w + pv.w;
  *(float4*)&x[m * Dn + c] = r;
}

// ---------------------------------------------------------------------------
// Weight converter -> MFMA B-fragment order.
// dst[((l*KC + kc)*NTtot + ntoff + nt)*512 + lane*8 + j8] = w[l][k][n] (bf16)
//   where k = kc*32 + (lane>>4)*8 + j8, n = nt*16 + (lane&15), zero if n >= C.
// ---------------------------------------------------------------------------
__global__ __launch_bounds__(256) void tcvt_frag(
    const float* __restrict__ src, u16* __restrict__ dst,
    int K, int C, int NTsub, int NTtot, int ntoff, int total)
{
  int t = blockIdx.x * 256 + threadIdx.x;
  if (t >= total) return;
  int j8 = t & 7;
  int lane = (t >> 3) & 63;
  int rest = t >> 9;
  int nt = rest % NTsub;
  int lkc = rest / NTsub;
  int KC = K >> 5;
  int kc = lkc % KC;
  int l = lkc / KC;
  int quad = lane >> 4, l16 = lane & 15;
  int k = kc * 32 + quad * 8 + j8;
  int n = nt * 16 + l16;
  float v = (n < C) ? src[((size_t)l * K + k) * C + n] : 0.f;
  dst[((size_t)(l * KC + kc) * NTtot + ntoff + nt) * 512 + lane * 8 + j8] = f2b(v);
}

extern "C" void kernel_launch(void* const* d_in, const int* in_sizes, int n_in,
                              void* d_out, int out_size, void* d_ws, size_t ws_size,
                              hipStream_t stream)
{
  (void)in_sizes; (void)n_in; (void)out_size;
  const int*   idx     = (const int*)d_in[0];
  const float* tok_emb = (const float*)d_in[1];
  const float* pos_emb = (const float*)d_in[2];
  const float* ln1_s   = (const float*)d_in[3];
  const float* ln1_b   = (const float*)d_in[4];
  const float* wq      = (const float*)d_in[5];
  const float* wk      = (const float*)d_in[6];
  const float* wv      = (const float*)d_in[7];
  const float* wo      = (const float*)d_in[8];
  const float* bo      = (const float*)d_in[9];
  const float* ln2_s   = (const float*)d_in[10];
  const float* ln2_b   = (const float*)d_in[11];
  const float* w1      = (const float*)d_in[12];
  const float* b1      = (const float*)d_in[13];
  const float* w2      = (const float*)d_in[14];
  const float* b2      = (const float*)d_in[15];
  const float* lnf_s   = (const float*)d_in[16];
  const float* lnf_b   = (const float*)d_in[17];
  const float* head_w  = (const float*)d_in[18];
  const float* head_b  = (const float*)d_in[19];
  float* out = (float*)d_out;

  // workspace layout (bytes)
  char* ws = (char*)d_ws;
  float* x  = (float*)(ws + 0);             // 50,331,648  fp32 residual stream
  u16*   h  = (u16*)(ws + 50331648);        // 25,165,824  LN output (bf16)
  u16*   qb = (u16*)(ws + 75497472);        // 25,165,824  (q,k,v contiguous!)
  u16*   kb = (u16*)(ws + 100663296);       // 25,165,824
  u16*   vb = (u16*)(ws + 125829120);       // 25,165,824  V^T [(b,h)][d][t]
  u16*   ab = (u16*)(ws + 150994944);       // 25,165,824  attn out
  u16* qkvT = (u16*)(ws + 176160768);       // 6 * 442368 (frag layout, NTtot=72)
  u16* woT  = qkvT + 6 * 442368;            // 6 * 147456 (NTtot=24)
  u16* w1T  = woT + 6 * 147456;             // 6 * 589824 (NTtot=96, K=384)
  u16* w2T  = w1T + 6 * 589824;             // 6 * 589824 (NTtot=24, K=1536)
  u16* hdT  = w2T + 6 * 589824;             // 49152 (NTtot=8, 95->128 pad)
  if (ws_size < (size_t)197492736) return;

  int tot = 6 * 384 * 384;
  tcvt_frag<<<(tot + 255) / 256, 256, 0, stream>>>(wq, qkvT, 384, 384, 24, 72, 0, tot);
  tcvt_frag<<<(tot + 255) / 256, 256, 0, stream>>>(wk, qkvT, 384, 384, 24, 72, 24, tot);
  tcvt_frag<<<(tot + 255) / 256, 256, 0, stream>>>(wv, qkvT, 384, 384, 24, 72, 48, tot);
  tcvt_frag<<<(tot + 255) / 256, 256, 0, stream>>>(wo, woT, 384, 384, 24, 24, 0, tot);
  tot = 6 * 384 * 1536;
  tcvt_frag<<<(tot + 255) / 256, 256, 0, stream>>>(w1, w1T, 384, 1536, 96, 96, 0, tot);
  tcvt_frag<<<(tot + 255) / 256, 256, 0, stream>>>(w2, w2T, 1536, 384, 24, 24, 0, tot);
  tot = 384 * 128;
  tcvt_frag<<<(tot + 255) / 256, 256, 0, stream>>>(head_w, hdT, 384, 95, 8, 8, 0, tot);

  embed_kernel<<<(Mn * 96) / 256, 256, 0, stream>>>(idx, tok_emb, pos_emb, x);
  ln_kernel<<<Mn / 4, 256, 0, stream>>>(x, ln1_s, ln1_b, h);   // layer-0 LN1

  for (int l = 0; l < 6; l++) {
    gemm_h<4, false, 6, 72><<<2304, 256, 0, stream>>>(h, qkvT + l * 442368, nullptr, nullptr, qb);
    attn_kernel<<<Bn * Hn * 4, 256, 0, stream>>>(qb, kb, vb, ab);
    // WO + residual + LN2 fused -> x, h
    gemm_ln<6><<<256, 512, 0, stream>>>(ab, woT + l * 147456, bo + l * Dn, x, x,
                                        ln2_s + l * Dn, ln2_b + l * Dn, h);
    // FFN1+relu+FFN2 + residual + LN1(next)/LNF fused -> x, h  (f1 eliminated)
    const float* ns = (l < 5) ? (ln1_s + (l + 1) * Dn) : lnf_s;
    const float* nb = (l < 5) ? (ln1_b + (l + 1) * Dn) : lnf_b;
    ffn_ln<<<256, 512, 0, stream>>>(h, w1T + l * 589824, b1 + l * FFn,
                                    w2T + l * 589824, b2 + l * Dn,
                                    x, x, ns, nb, h);
  }
  gemm_h<3, false, 6, 8><<<256, 256, 0, stream>>>(h, hdT, head_b, nullptr, out);
}

// Round 12
// 1504.784 us; speedup vs baseline: 1.4616x; 1.0407x over previous
//
#include <hip/hip_runtime.h>
#include <hip/hip_bf16.h>
#include <cstdint>

#define DEV __device__ __forceinline__

typedef __hip_bfloat16 bf16;
typedef unsigned short u16;
typedef unsigned int u32;
typedef __attribute__((ext_vector_type(8))) short s8v;   // 8 bf16 (4 VGPRs) MFMA A/B frag
typedef __attribute__((ext_vector_type(4))) float f4;    // MFMA C/D frag

static constexpr int Bn = 128;
static constexpr int Tn = 256;
static constexpr int Dn = 384;
static constexpr int Hn = 6;
static constexpr int HDn = 64;
static constexpr int FFn = 1536;
static constexpr int Vn = 95;
static constexpr int Mn = Bn * 256;   // 32768

DEV u16 f2b(float f) {
  bf16 h = __float2bfloat16(f);
  return *reinterpret_cast<u16*>(&h);
}
DEV u32 pk2(float a, float b) { return (u32)f2b(a) | ((u32)f2b(b) << 16); }

// async 16B global->LDS. LDS destination is wave-uniform base + lane*16.
DEV void gl_lds16(const void* g, void* l) {
  auto gp = (const __attribute__((address_space(1))) u32*)(uintptr_t)g;
  auto lp = (__attribute__((address_space(3))) u32*)(u32)(uintptr_t)l;
  __builtin_amdgcn_global_load_lds(gp, lp, 16, 0, 0);
}

// counted vmcnt with literal immediate (folds under full unroll)
DEV void waitvm(int n) {
  if (n == 0)       asm volatile("s_waitcnt vmcnt(0)" ::: "memory");
  else if (n == 2)  asm volatile("s_waitcnt vmcnt(2)" ::: "memory");
  else if (n == 4)  asm volatile("s_waitcnt vmcnt(4)" ::: "memory");
  else if (n == 6)  asm volatile("s_waitcnt vmcnt(6)" ::: "memory");
  else if (n == 8)  asm volatile("s_waitcnt vmcnt(8)" ::: "memory");
  else if (n == 12) asm volatile("s_waitcnt vmcnt(12)" ::: "memory");
  else              asm volatile("s_waitcnt vmcnt(16)" ::: "memory");
}

// ---------------------------------------------------------------------------
// Hybrid GEMM — R4 single-barrier pipelined schedule (QKV / head).
// MODE 0: bf16 out [M,N]   MODE 3: f32 head out [M,95] col-guarded
// MODE 4: fused QKV: n<384 q; n<768 k; n>=768 v in vT layout [(b,h)][d][t]
// ---------------------------------------------------------------------------
template <int MODE, bool RELU, int NKT, int NT>
__global__ __launch_bounds__(256, 2) void gemm_h(
    const u16* __restrict__ A, const u16* __restrict__ Bw,
    const float* __restrict__ bias, const float* __restrict__ resid,
    void* __restrict__ outp)
{
  constexpr int K = NKT * 64;
  constexpr int N = NT * 16;
  constexpr int nTiles = NT / 8;
  __shared__ __align__(16) u16 As[3][128 * 64];
  const int tid = threadIdx.x;
  const int lane = tid & 63, wave = tid >> 6;
  const int quad = lane >> 4, l16 = lane & 15;
  const int wy = wave >> 1, wx = wave & 1;
  const int blk = blockIdx.x;
  const int xcd = blk & 7, tt = blk >> 3;
  const int nT = tt % nTiles, mT = xcd + 8 * (tt / nTiles);
  const int mBase = mT * 128, nBase = nT * 128;

  f4 acc[4][4] = {};

  int rS[4], cS[4];
#pragma unroll
  for (int i = 0; i < 4; i++) {
    int s = i * 256 + tid;
    rS[i] = s >> 3;
    cS[i] = ((s & 7) ^ (rS[i] & 7)) * 8;
  }

  const u16* Ab = A + (size_t)mBase * K;
  const u16* Bp = Bw + (size_t)((nBase >> 4) + wx * 4) * 512 + lane * 8;

#define STAGEA(buf, kt)                                                       \
  do {                                                                        \
    _Pragma("unroll")                                                         \
    for (int i = 0; i < 4; i++)                                               \
      gl_lds16(Ab + (size_t)rS[i] * K + (kt) + cS[i],                         \
               &As[buf][(i * 256 + wave * 64) * 8]);                          \
  } while (0)

  // prologue: issue order MUST be stage(0), bqa(0), stage(1)
  s8v bqa[2][4];
  STAGEA(0, 0);
  __builtin_amdgcn_sched_barrier(0);
#pragma unroll
  for (int j = 0; j < 4; j++)
    bqa[0][j] = *(const s8v*)(Bp + (size_t)0 * (NT * 512) + j * 512);
  __builtin_amdgcn_sched_barrier(0);
  STAGEA(1, 64);
  __builtin_amdgcn_sched_barrier(0);

  const int nk = NKT;
#pragma unroll
  for (int ik = 0; ik < nk; ik++) {
    const int cur = ik % 3;
    const int par = ik & 1;
    waitvm((ik + 1 < nk) ? 4 : 0);
    asm volatile("s_barrier" ::: "memory");
    s8v bqb[4];
#pragma unroll
    for (int j = 0; j < 4; j++)
      bqb[j] = *(const s8v*)(Bp + (size_t)(ik * 2 + 1) * (NT * 512) + j * 512);
    __builtin_amdgcn_sched_barrier(0);
    if (ik + 1 < nk) {
#pragma unroll
      for (int j = 0; j < 4; j++)
        bqa[par ^ 1][j] = *(const s8v*)(Bp + (size_t)(ik * 2 + 2) * (NT * 512) + j * 512);
    }
    __builtin_amdgcn_sched_barrier(0);
    if (ik + 2 < nk) STAGEA((ik + 2) % 3, (ik + 2) * 64);
    __builtin_amdgcn_sched_barrier(0);
    {
      s8v af[4];
#pragma unroll
      for (int i = 0; i < 4; i++) {
        int row = wy * 64 + i * 16 + l16;
        int ch = quad ^ (row & 7);
        af[i] = *(const s8v*)&As[cur][row * 64 + ch * 8];
      }
#pragma unroll
      for (int i = 0; i < 4; i++)
#pragma unroll
        for (int j = 0; j < 4; j++)
          acc[i][j] = __builtin_amdgcn_mfma_f32_16x16x32_bf16(af[i], bqa[par][j], acc[i][j], 0, 0, 0);
    }
    waitvm(4 * ((ik + 1 < nk) + (ik + 2 < nk)));
    {
      s8v af[4];
#pragma unroll
      for (int i = 0; i < 4; i++) {
        int row = wy * 64 + i * 16 + l16;
        int ch = (4 + quad) ^ (row & 7);
        af[i] = *(const s8v*)&As[cur][row * 64 + ch * 8];
      }
#pragma unroll
      for (int i = 0; i < 4; i++)
#pragma unroll
        for (int j = 0; j < 4; j++)
          acc[i][j] = __builtin_amdgcn_mfma_f32_16x16x32_bf16(af[i], bqb[j], acc[i][j], 0, 0, 0);
    }
  }
#undef STAGEA

  if (MODE == 0) {
    u16* out = (u16*)outp;
#pragma unroll
    for (int j = 0; j < 4; j++) {
      int n = nBase + wx * 64 + j * 16 + l16;
      float bv = bias ? bias[n] : 0.f;
#pragma unroll
      for (int i = 0; i < 4; i++) {
        int m0 = mBase + wy * 64 + i * 16 + quad * 4;
#pragma unroll
        for (int r = 0; r < 4; r++) {
          float v = acc[i][j][r] + bv;
          if (RELU) v = fmaxf(v, 0.f);
          out[(size_t)(m0 + r) * N + n] = f2b(v);
        }
      }
    }
  } else if (MODE == 3) {
    float* out = (float*)outp;
#pragma unroll
    for (int j = 0; j < 4; j++) {
      int n = nBase + wx * 64 + j * 16 + l16;
      if (n < Vn) {
        float bv = bias[n];
#pragma unroll
        for (int i = 0; i < 4; i++) {
          int m0 = mBase + wy * 64 + i * 16 + quad * 4;
#pragma unroll
          for (int r = 0; r < 4; r++)
            out[(size_t)(m0 + r) * Vn + n] = acc[i][j][r] + bv;
        }
      }
    }
  } else if (MODE == 4) {
    u16* qb = (u16*)outp;
    u16* kb = qb + (size_t)Mn * 384;
    u16* vb = kb + (size_t)Mn * 384;
#pragma unroll
    for (int j = 0; j < 4; j++) {
      int n = nBase + wx * 64 + j * 16 + l16;
      if (n < 768) {
        u16* dst = (n < 384) ? qb : kb;
        int col = (n < 384) ? n : (n - 384);   // 384 is NOT pow2 — no mask!
#pragma unroll
        for (int i = 0; i < 4; i++) {
          int m0 = mBase + wy * 64 + i * 16 + quad * 4;
#pragma unroll
          for (int r = 0; r < 4; r++)
            dst[(size_t)(m0 + r) * 384 + col] = f2b(acc[i][j][r]);
        }
      } else {
        int n7 = n - 768;
        int hh = n7 >> 6, d = n7 & 63;
#pragma unroll
        for (int i = 0; i < 4; i++) {
          int m0 = mBase + wy * 64 + i * 16 + quad * 4;
          int b = m0 >> 8, t0 = m0 & 255;
          uint2 w;
          w.x = pk2(acc[i][j][0], acc[i][j][1]);
          w.y = pk2(acc[i][j][2], acc[i][j][3]);
          *(uint2*)&vb[((b * Hn + hh) * HDn + d) * Tn + t0] = w;
        }
      }
    }
  }
}

// ---------------------------------------------------------------------------
// WO GEMM + residual-add + LayerNorm fusion (N=384 full-row tile), R6 form.
// At the mixed-rw traffic ceiling (~61us = 170MB / 2.8 TB/s) — unchanged.
// ---------------------------------------------------------------------------
template <int NKT>
__global__ __launch_bounds__(512, 2) void gemm_ln(
    const u16* __restrict__ A, const u16* __restrict__ Bw,
    const float* __restrict__ bias, const float* __restrict__ resid,
    float* __restrict__ xout,
    const float* __restrict__ sc, const float* __restrict__ bi,
    u16* __restrict__ hout)
{
  constexpr int K = NKT * 64;
  constexpr int NT = 24;               // 384 / 16
  __shared__ __align__(16) u16 As[2][128 * 64];
  __shared__ __align__(16) u16 Bs[2][24576];      // 2 ks x 24 nt x 512
  __shared__ float2 red[4][128];
  const int tid = threadIdx.x;
  const int lane = tid & 63, wave = tid >> 6;       // 0..7
  const int quad = lane >> 4, l16 = lane & 15;
  const int wy = wave >> 2, wx = wave & 3;          // 2 x 4
  const int blk = blockIdx.x;
  const int mT = (blk & 7) + 8 * (blk >> 3);        // XCD-major
  const int mBase = mT * 128;

  f4 acc[4][6] = {};

  int rS[2], cS[2];
#pragma unroll
  for (int i = 0; i < 2; i++) {
    int s = i * 512 + tid;
    rS[i] = s >> 3;
    cS[i] = ((s & 7) ^ (rS[i] & 7)) * 8;
  }

  const u16* Ab = A + (size_t)mBase * K;

#define STAGEL(buf, kt)                                                       \
  do {                                                                        \
    _Pragma("unroll")                                                         \
    for (int i = 0; i < 2; i++)                                               \
      gl_lds16(Ab + (size_t)rS[i] * K + (kt) + cS[i],                         \
               &As[buf][(i * 512 + wave * 64) * 8]);                          \
  } while (0)

#define STAGEB2(buf, ikk)                                                     \
  do {                                                                        \
    _Pragma("unroll")                                                         \
    for (int L = 0; L < 6; L++) {                                             \
      int ks = L / 3, th = L % 3;                                             \
      int c = th * 4096 + tid * 8;                                            \
      gl_lds16(Bw + (size_t)((ikk) * 2 + ks) * (NT * 512) + c,                \
               &Bs[buf][ks * 12288 + c]);                                     \
    }                                                                         \
  } while (0)

  STAGEL(0, 0);
  STAGEB2(0, 0);

  const int nk = NKT;
#pragma unroll
  for (int ik = 0; ik < nk; ik++) {
    const int cur = ik & 1;
    asm volatile("s_waitcnt vmcnt(0)" ::: "memory");
    asm volatile("s_barrier" ::: "memory");
    if (ik + 1 < nk) {
      STAGEL(cur ^ 1, (ik + 1) * 64);
      STAGEB2(cur ^ 1, ik + 1);
    }
    __builtin_amdgcn_sched_barrier(0);
#pragma unroll
    for (int ks = 0; ks < 2; ks++) {
      s8v af[4], bq[6];
#pragma unroll
      for (int i = 0; i < 4; i++) {
        int row = wy * 64 + i * 16 + l16;
        int ch = (ks * 4 + quad) ^ (row & 7);
        af[i] = *(const s8v*)&As[cur][row * 64 + ch * 8];
      }
#pragma unroll
      for (int j = 0; j < 6; j++)
        bq[j] = *(const s8v*)&Bs[cur][ks * 12288 + (wx * 6 + j) * 512 + lane * 8];
#pragma unroll
      for (int i = 0; i < 4; i++)
#pragma unroll
        for (int j = 0; j < 6; j++)
          acc[i][j] = __builtin_amdgcn_mfma_f32_16x16x32_bf16(af[i], bq[j], acc[i][j], 0, 0, 0);
    }
  }
#undef STAGEL
#undef STAGEB2

  // ---- epilogue: x = resid + C + bias; row stats; h = LN(x)*sc + bi ----
  f4 psum[4] = {}, psq[4] = {};
#pragma unroll
  for (int j = 0; j < 6; j++) {
    int n = wx * 96 + j * 16 + l16;
    float bv = bias[n];
#pragma unroll
    for (int i = 0; i < 4; i++) {
      int m0 = mBase + wy * 64 + i * 16 + quad * 4;
#pragma unroll
      for (int r = 0; r < 4; r++) {
        int m = m0 + r;
        float v = resid[(size_t)m * Dn + n] + acc[i][j][r] + bv;
        xout[(size_t)m * Dn + n] = v;
        acc[i][j][r] = v;
        psum[i][r] += v;
        psq[i][r] += v * v;
      }
    }
  }
#pragma unroll
  for (int o = 1; o < 16; o <<= 1)
#pragma unroll
    for (int i = 0; i < 4; i++)
#pragma unroll
      for (int r = 0; r < 4; r++) {
        psum[i][r] += __shfl_xor(psum[i][r], o);
        psq[i][r] += __shfl_xor(psq[i][r], o);
      }
  if (l16 == 0) {
#pragma unroll
    for (int i = 0; i < 4; i++)
#pragma unroll
      for (int r = 0; r < 4; r++) {
        int lr = wy * 64 + i * 16 + quad * 4 + r;
        float2 p; p.x = psum[i][r]; p.y = psq[i][r];
        red[wx][lr] = p;
      }
  }
  __syncthreads();
  float scv[6], biv[6];
#pragma unroll
  for (int j = 0; j < 6; j++) {
    int n = wx * 96 + j * 16 + l16;
    scv[j] = sc[n];
    biv[j] = bi[n];
  }
#pragma unroll
  for (int i = 0; i < 4; i++)
#pragma unroll
    for (int r = 0; r < 4; r++) {
      int lr = wy * 64 + i * 16 + quad * 4 + r;
      float ts = 0.f, tq = 0.f;
#pragma unroll
      for (int w = 0; w < 4; w++) { float2 p = red[w][lr]; ts += p.x; tq += p.y; }
      float mean = ts * (1.f / 384.f);
      float inv = rsqrtf(tq * (1.f / 384.f) - mean * mean + 1e-5f);
      int m = mBase + lr;
#pragma unroll
      for (int j = 0; j < 6; j++) {
        int n = wx * 96 + j * 16 + l16;
        hout[(size_t)m * Dn + n] = f2b((acc[i][j][r] - mean) * inv * scv[j] + biv[j]);
      }
    }
}

// ---------------------------------------------------------------------------
// R12: FUSED FFN v5 — all three HW-verified pieces composed:
//  (a) Hs as 6 As-style subtiles [128][64]+XOR (R11: conflicts 7.08M->2.36M)
//  (b) Ps double-buffer + ONE barrier/segment + red aliases Ps0 (R11)
//  (c) R7's B-fragment prefetch: bq1[2][4] ik-parity dbuf w/ waitvm(4);
//      bq2[0] issued after GEMM1 drain (covered by P-write VALU);
//      bq2[2][6] ks2-parity dbuf w/ waitvm(6). R11's regression (148 vs
//      103us) was dropping exactly this — every inner step ate raw L2
//      latency on the B path.
// vmcnt carry-over: each segment starts & ends drained (GEMM1's last
// waitvm(0) / GEMM2's last waitvm(0)), so R7's counts apply unchanged.
// LDS 160KB exactly, 1 block/CU.
// ---------------------------------------------------------------------------
__global__ __launch_bounds__(512, 2) void ffn_ln(
    const u16* __restrict__ A, const u16* __restrict__ B1w,
    const float* __restrict__ b1, const u16* __restrict__ B2w,
    const float* __restrict__ b2, const float* __restrict__ resid,
    float* __restrict__ xout,
    const float* __restrict__ sc, const float* __restrict__ bi,
    u16* __restrict__ hout)
{
  __shared__ __align__(16) u16 LDSu[81920];   // 160 KB total
  u16* Hs  = LDSu;            // 6 subtiles x [128][64] = 49152 u16 (96 KB)
  u16* Ps0 = LDSu + 49152;    // 16384 u16 (32 KB)
  u16* Ps1 = LDSu + 65536;    // 16384 u16 (32 KB)
  const int tid = threadIdx.x;
  const int lane = tid & 63, wave = tid >> 6;
  const int quad = lane >> 4, l16 = lane & 15;
  const int wy = wave >> 2, wx = wave & 3;         // 2 x 4
  const int mT = (blockIdx.x & 7) + 8 * (blockIdx.x >> 3);
  const int mBase = mT * 128;

  const u16* hg = A + (size_t)mBase * Dn;

  // ---- stage Hs (R11-verified): slot S: ik=S>>10, row=(S&1023)>>3,
  // chunk-slot c=S&7 holds source chunk c^(row&7) of col-group ik. ----
#pragma unroll
  for (int i = 0; i < 12; i++) {
    u32 S = i * 512 + tid;
    u32 ik = S >> 10, s_in = S & 1023;
    u32 row = s_in >> 3, c = s_in & 7;
    u32 src = ik * 64 + (c ^ (row & 7)) * 8;
    gl_lds16(hg + (size_t)row * Dn + src, &Hs[S * 8]);
  }
  asm volatile("s_waitcnt vmcnt(0)" ::: "memory");
  asm volatile("s_barrier" ::: "memory");

  const u16* B1p = B1w + (size_t)(wx * 2) * 512 + lane * 8;
  const u16* B2p = B2w + (size_t)(wx * 6) * 512 + lane * 8;

  f4 acc2[4][6] = {};
  s8v bq2[2][6];

#pragma unroll 1
  for (int seg = 0; seg <= 12; seg++) {
    // ---------------- GEMM1 on chunk seg: P = relu(h @ W1[:,seg*128..]+b1)
    if (seg < 12) {
      const int c = seg;
      float4 b1v0 = *(const float4*)&b1[c * 128 + wx * 32 + quad * 4];
      float4 b1v1 = *(const float4*)&b1[c * 128 + wx * 32 + 16 + quad * 4];
      __builtin_amdgcn_sched_barrier(0);
      s8v bq1[2][4];
#pragma unroll
      for (int u = 0; u < 4; u++) {
        int ks = u >> 1, j = u & 1;
        bq1[0][u] = *(const s8v*)(B1p + (size_t)(ks * 96 + c * 8 + j) * 512);
      }
      __builtin_amdgcn_sched_barrier(0);
      f4 acc1[4][2] = {};
#pragma unroll
      for (int ik = 0; ik < 6; ik++) {
        const int par = ik & 1;
        if (ik + 1 < 6) {
#pragma unroll
          for (int u = 0; u < 4; u++) {
            int ks = u >> 1, j = u & 1;
            bq1[par ^ 1][u] = *(const s8v*)(B1p + (size_t)(((ik + 1) * 2 + ks) * 96 + c * 8 + j) * 512);
          }
        }
        __builtin_amdgcn_sched_barrier(0);
        waitvm((ik + 1 < 6) ? 4 : 0);   // retire bq1[par] (+b1v at ik=0)
#pragma unroll
        for (int ks = 0; ks < 2; ks++) {
          s8v af[4];
#pragma unroll
          for (int i = 0; i < 4; i++) {
            int row = wy * 64 + i * 16 + l16;
            int chx = (ks * 4 + quad) ^ (row & 7);
            af[i] = *(const s8v*)&Hs[ik * 8192 + row * 64 + chx * 8];
          }
#pragma unroll
          for (int i = 0; i < 4; i++)
#pragma unroll
            for (int j = 0; j < 2; j++)
              acc1[i][j] = __builtin_amdgcn_mfma_f32_16x16x32_bf16(
                  bq1[par][ks * 2 + j], af[i], acc1[i][j], 0, 0, 0);
        }
      }
      // prefetch bq2[0] for THIS segment's GEMM2 (cc=seg-1) — pure global,
      // P-write VALU below covers its latency (R7 pattern).
      if (seg >= 1) {
        const int cc = seg - 1;
#pragma unroll
        for (int j = 0; j < 6; j++)
          bq2[0][j] = *(const s8v*)(B2p + (size_t)((cc * 4) * 24 + j) * 512);
      }
      __builtin_amdgcn_sched_barrier(0);
      // P write: bias + relu + pack; swizzled uint2 stores into Ps[c&1]
      char* Pb = (char*)((c & 1) ? Ps1 : Ps0);
#pragma unroll
      for (int i = 0; i < 4; i++) {
        int m = wy * 64 + i * 16 + l16;
#pragma unroll
        for (int j = 0; j < 2; j++) {
          float4 bv4 = (j == 0) ? b1v0 : b1v1;
          float v0 = fmaxf(acc1[i][j][0] + bv4.x, 0.f);
          float v1 = fmaxf(acc1[i][j][1] + bv4.y, 0.f);
          float v2 = fmaxf(acc1[i][j][2] + bv4.z, 0.f);
          float v3 = fmaxf(acc1[i][j][3] + bv4.w, 0.f);
          uint2 w; w.x = pk2(v0, v1); w.y = pk2(v2, v3);
          int byteoff = (m * 256 + (wx * 32 + j * 16 + quad * 4) * 2) ^ ((m & 7) << 4);
          *(uint2*)(Pb + byteoff) = w;
        }
      }
    } else {
      // seg == 12: no GEMM1 — issue bq2[0] for cc=11 directly
      const int cc = 11;
#pragma unroll
      for (int j = 0; j < 6; j++)
        bq2[0][j] = *(const s8v*)(B2p + (size_t)((cc * 4) * 24 + j) * 512);
      __builtin_amdgcn_sched_barrier(0);
    }
    // ---------------- GEMM2 on chunk seg-1: acc2 += P @ W2[cc*128.., :]
    if (seg >= 1) {
      const int cc = seg - 1;
      const char* Pb = (const char*)((cc & 1) ? Ps1 : Ps0);
#pragma unroll
      for (int ks2 = 0; ks2 < 4; ks2++) {
        const int p2 = ks2 & 1;
        if (ks2 + 1 < 4) {
#pragma unroll
          for (int j = 0; j < 6; j++)
            bq2[p2 ^ 1][j] = *(const s8v*)(B2p + (size_t)((cc * 4 + ks2 + 1) * 24 + j) * 512);
        }
        __builtin_amdgcn_sched_barrier(0);
        waitvm((ks2 + 1 < 4) ? 6 : 0);
        s8v af2[4];
#pragma unroll
        for (int i = 0; i < 4; i++) {
          int m = wy * 64 + i * 16 + l16;
          int byteoff = (m * 256 + (ks2 * 4 + quad) * 16) ^ ((m & 7) << 4);
          af2[i] = *(const s8v*)(Pb + byteoff);
        }
#pragma unroll
        for (int i = 0; i < 4; i++)
#pragma unroll
          for (int j = 0; j < 6; j++)
            acc2[i][j] = __builtin_amdgcn_mfma_f32_16x16x32_bf16(
                af2[i], bq2[p2][j], acc2[i][j], 0, 0, 0);
      }
    }
    asm volatile("s_waitcnt lgkmcnt(0)" ::: "memory");
    asm volatile("s_barrier" ::: "memory");
  }

  // ---- epilogue: x = resid + acc2 + b2; row stats; h' = LN(x)*sc+bi ----
  // red aliases Ps0 (all Ps reads completed before the final seg barrier).
  float2* red = (float2*)Ps0;   // red[wx*128 + lr]
  f4 psum[4] = {}, psq[4] = {};
#pragma unroll
  for (int j = 0; j < 6; j++) {
    int n = wx * 96 + j * 16 + l16;
    float bv = b2[n];
#pragma unroll
    for (int i = 0; i < 4; i++) {
      int m0 = mBase + wy * 64 + i * 16 + quad * 4;
#pragma unroll
      for (int r = 0; r < 4; r++) {
        int m = m0 + r;
        float v = resid[(size_t)m * Dn + n] + acc2[i][j][r] + bv;
        xout[(size_t)m * Dn + n] = v;
        acc2[i][j][r] = v;
        psum[i][r] += v;
        psq[i][r] += v * v;
      }
    }
  }
#pragma unroll
  for (int o = 1; o < 16; o <<= 1)
#pragma unroll
    for (int i = 0; i < 4; i++)
#pragma unroll
      for (int r = 0; r < 4; r++) {
        psum[i][r] += __shfl_xor(psum[i][r], o);
        psq[i][r] += __shfl_xor(psq[i][r], o);
      }
  if (l16 == 0) {
#pragma unroll
    for (int i = 0; i < 4; i++)
#pragma unroll
      for (int r = 0; r < 4; r++) {
        int lr = wy * 64 + i * 16 + quad * 4 + r;
        float2 p; p.x = psum[i][r]; p.y = psq[i][r];
        red[wx * 128 + lr] = p;
      }
  }
  __syncthreads();
  float scv[6], biv[6];
#pragma unroll
  for (int j = 0; j < 6; j++) {
    int n = wx * 96 + j * 16 + l16;
    scv[j] = sc[n];
    biv[j] = bi[n];
  }
#pragma unroll
  for (int i = 0; i < 4; i++)
#pragma unroll
    for (int r = 0; r < 4; r++) {
      int lr = wy * 64 + i * 16 + quad * 4 + r;
      float ts = 0.f, tq = 0.f;
#pragma unroll
      for (int w = 0; w < 4; w++) { float2 p = red[w * 128 + lr]; ts += p.x; tq += p.y; }
      float mean = ts * (1.f / 384.f);
      float inv = rsqrtf(tq * (1.f / 384.f) - mean * mean + 1e-5f);
      int m = mBase + lr;
#pragma unroll
      for (int j = 0; j < 6; j++) {
        int n = wx * 96 + j * 16 + l16;
        hout[(size_t)m * Dn + n] = f2b((acc2[i][j][r] - mean) * inv * scv[j] + biv[j]);
      }
    }
}

// ---------------------------------------------------------------------------
// Flash-chunked attention v2 (unchanged).
// ---------------------------------------------------------------------------
__global__ __launch_bounds__(256) void attn_kernel(
    const u16* __restrict__ q, const u16* __restrict__ k,
    const u16* __restrict__ vT, u16* __restrict__ ao)
{
  __shared__ __align__(16) u16 Psh[4][2][16 * 40];
  const int tid = threadIdx.x, lane = tid & 63, wave = tid >> 6;
  const int quad = lane >> 4, l16 = lane & 15;
  const int c4 = blockIdx.x / 768;
  const int bh = blockIdx.x - c4 * 768;
  const int b = bh / Hn, h = bh % Hn;
  const u16* qg = q + (b * Tn) * Dn + h * HDn;
  const u16* kg = k + (b * Tn) * Dn + h * HDn;
  const u16* vg = vT + bh * (HDn * Tn);
  u16* aog = ao + (b * Tn) * Dn + h * HDn;
  const float c1 = 0.125f * 1.44269504f;  // scale * log2(e)

  const int qt = (wave & 2) ? ((wave & 1) ? 15 - c4 : 8 + c4)
                            : ((wave & 1) ? 7 - c4 : c4);
  const int qglob = qt * 16 + l16;

  const s8v qf0 = *(const s8v*)&qg[qglob * Dn + quad * 8];
  const s8v qf1 = *(const s8v*)&qg[qglob * Dn + 32 + quad * 8];

  float lsum = 0.f;
  f4 O[4] = {};

  const int nch = qt / 2 + 1;
  for (int c2 = 0; c2 < nch; c2++) {
    const int kk0 = c2 * 32;
    f4 S0 = {0.f, 0.f, 0.f, 0.f}, S1 = S0;
    {
      s8v kf = *(const s8v*)&kg[(kk0 + l16) * Dn + quad * 8];
      S0 = __builtin_amdgcn_mfma_f32_16x16x32_bf16(kf, qf0, S0, 0, 0, 0);
      kf = *(const s8v*)&kg[(kk0 + l16) * Dn + 32 + quad * 8];
      S0 = __builtin_amdgcn_mfma_f32_16x16x32_bf16(kf, qf1, S0, 0, 0, 0);
    }
    if (kk0 + 16 <= qt * 16) {
      s8v kf = *(const s8v*)&kg[(kk0 + 16 + l16) * Dn + quad * 8];
      S1 = __builtin_amdgcn_mfma_f32_16x16x32_bf16(kf, qf0, S1, 0, 0, 0);
      kf = *(const s8v*)&kg[(kk0 + 16 + l16) * Dn + 32 + quad * 8];
      S1 = __builtin_amdgcn_mfma_f32_16x16x32_bf16(kf, qf1, S1, 0, 0, 0);
    }
    const int kkq = kk0 + quad * 4;
    f4 E0, E1;
#pragma unroll
    for (int r = 0; r < 4; r++) {
      E0[r] = (kkq + r <= qglob) ? exp2f(S0[r] * c1) : 0.f;
      E1[r] = (kkq + 16 + r <= qglob) ? exp2f(S1[r] * c1) : 0.f;
      lsum += E0[r] + E1[r];
    }
    u16* prow = &Psh[wave][c2 & 1][l16 * 40];
    uint2 w0, w1;
    w0.x = pk2(E0[0], E0[1]); w0.y = pk2(E0[2], E0[3]);
    w1.x = pk2(E1[0], E1[1]); w1.y = pk2(E1[2], E1[3]);
    *(uint2*)&prow[quad * 4] = w0;
    *(uint2*)&prow[16 + quad * 4] = w1;
    const s8v pf = *(const s8v*)&prow[quad * 8];
#pragma unroll
    for (int dm = 0; dm < 4; dm++) {
      s8v vf = *(const s8v*)&vg[(dm * 16 + l16) * Tn + kk0 + quad * 8];
      O[dm] = __builtin_amdgcn_mfma_f32_16x16x32_bf16(vf, pf, O[dm], 0, 0, 0);
    }
  }

  lsum += __shfl_xor(lsum, 16);
  lsum += __shfl_xor(lsum, 32);
  const float inv = 1.0f / lsum;
#pragma unroll
  for (int dm = 0; dm < 4; dm++) {
    uint2 w;
    w.x = pk2(O[dm][0] * inv, O[dm][1] * inv);
    w.y = pk2(O[dm][2] * inv, O[dm][3] * inv);
    *(uint2*)&aog[qglob * Dn + dm * 16 + quad * 4] = w;
  }
}

// ---------------------------------------------------------------------------
// LayerNorm: one wave per token — used ONCE (after embed, layer-0 LN1).
// ---------------------------------------------------------------------------
__global__ __launch_bounds__(256) void ln_kernel(
    const float* __restrict__ x, const float* __restrict__ sc,
    const float* __restrict__ bi, u16* __restrict__ out)
{
  int tok = blockIdx.x * 4 + (threadIdx.x >> 6);
  int lane = threadIdx.x & 63;
  const float* xr = x + (size_t)tok * Dn;
  float v[6];
  float s = 0.f, sq = 0.f;
#pragma unroll
  for (int i = 0; i < 6; i++) {
    v[i] = xr[lane + 64 * i];
    s += v[i];
    sq += v[i] * v[i];
  }
#pragma unroll
  for (int o = 1; o < 64; o <<= 1) {
    s += __shfl_xor(s, o);
    sq += __shfl_xor(sq, o);
  }
  float mean = s * (1.f / 384.f);
  float var = sq * (1.f / 384.f) - mean * mean;
  float inv = rsqrtf(var + 1e-5f);
  u16* orow = out + (size_t)tok * Dn;
#pragma unroll
  for (int i = 0; i < 6; i++) {
    int c = lane + 64 * i;
    orow[c] = f2b((v[i] - mean) * inv * sc[c] + bi[c]);
  }
}

// x[m][:] = tok_emb[idx[m]][:] + pos_emb[m%T][:]  (float4 per thread)
__global__ __launch_bounds__(256) void embed_kernel(
    const int* __restrict__ idx, const float* __restrict__ tok,
    const float* __restrict__ pos, float* __restrict__ x)
{
  int i = blockIdx.x * 256 + threadIdx.x;  // [0, M*96)
  int m = i / 96, c = (i - m * 96) * 4;
  int t = m & (Tn - 1);
  const float4 tv = *(const float4*)&tok[idx[m] * Dn + c];
  const float4 pv = *(const float4*)&pos[t * Dn + c];
  float4 r;
  r.x = tv.x + pv.x; r.y = tv.y + pv.y; r.z = tv.z + pv.z; r.w = tv.w + pv.w;
  *(float4*)&x[m * Dn + c] = r;
}

// ---------------------------------------------------------------------------
// Weight converter -> MFMA B-fragment order.
// dst[((l*KC + kc)*NTtot + ntoff + nt)*512 + lane*8 + j8] = w[l][k][n] (bf16)
//   where k = kc*32 + (lane>>4)*8 + j8, n = nt*16 + (lane&15), zero if n >= C.
// ---------------------------------------------------------------------------
__global__ __launch_bounds__(256) void tcvt_frag(
    const float* __restrict__ src, u16* __restrict__ dst,
    int K, int C, int NTsub, int NTtot, int ntoff, int total)
{
  int t = blockIdx.x * 256 + threadIdx.x;
  if (t >= total) return;
  int j8 = t & 7;
  int lane = (t >> 3) & 63;
  int rest = t >> 9;
  int nt = rest % NTsub;
  int lkc = rest / NTsub;
  int KC = K >> 5;
  int kc = lkc % KC;
  int l = lkc / KC;
  int quad = lane >> 4, l16 = lane & 15;
  int k = kc * 32 + quad * 8 + j8;
  int n = nt * 16 + l16;
  float v = (n < C) ? src[((size_t)l * K + k) * C + n] : 0.f;
  dst[((size_t)(l * KC + kc) * NTtot + ntoff + nt) * 512 + lane * 8 + j8] = f2b(v);
}

extern "C" void kernel_launch(void* const* d_in, const int* in_sizes, int n_in,
                              void* d_out, int out_size, void* d_ws, size_t ws_size,
                              hipStream_t stream)
{
  (void)in_sizes; (void)n_in; (void)out_size;
  const int*   idx     = (const int*)d_in[0];
  const float* tok_emb = (const float*)d_in[1];
  const float* pos_emb = (const float*)d_in[2];
  const float* ln1_s   = (const float*)d_in[3];
  const float* ln1_b   = (const float*)d_in[4];
  const float* wq      = (const float*)d_in[5];
  const float* wk      = (const float*)d_in[6];
  const float* wv      = (const float*)d_in[7];
  const float* wo      = (const float*)d_in[8];
  const float* bo      = (const float*)d_in[9];
  const float* ln2_s   = (const float*)d_in[10];
  const float* ln2_b   = (const float*)d_in[11];
  const float* w1      = (const float*)d_in[12];
  const float* b1      = (const float*)d_in[13];
  const float* w2      = (const float*)d_in[14];
  const float* b2      = (const float*)d_in[15];
  const float* lnf_s   = (const float*)d_in[16];
  const float* lnf_b   = (const float*)d_in[17];
  const float* head_w  = (const float*)d_in[18];
  const float* head_b  = (const float*)d_in[19];
  float* out = (float*)d_out;

  // workspace layout (bytes)
  char* ws = (char*)d_ws;
  float* x  = (float*)(ws + 0);             // 50,331,648  fp32 residual stream
  u16*   h  = (u16*)(ws + 50331648);        // 25,165,824  LN output (bf16)
  u16*   qb = (u16*)(ws + 75497472);        // 25,165,824  (q,k,v contiguous!)
  u16*   kb = (u16*)(ws + 100663296);       // 25,165,824
  u16*   vb = (u16*)(ws + 125829120);       // 25,165,824  V^T [(b,h)][d][t]
  u16*   ab = (u16*)(ws + 150994944);       // 25,165,824  attn out
  u16* qkvT = (u16*)(ws + 176160768);       // 6 * 442368 (frag layout, NTtot=72)
  u16* woT  = qkvT + 6 * 442368;            // 6 * 147456 (NTtot=24)
  u16* w1T  = woT + 6 * 147456;             // 6 * 589824 (NTtot=96, K=384)
  u16* w2T  = w1T + 6 * 589824;             // 6 * 589824 (NTtot=24, K=1536)
  u16* hdT  = w2T + 6 * 589824;             // 49152 (NTtot=8, 95->128 pad)
  if (ws_size < (size_t)197492736) return;

  int tot = 6 * 384 * 384;
  tcvt_frag<<<(tot + 255) / 256, 256, 0, stream>>>(wq, qkvT, 384, 384, 24, 72, 0, tot);
  tcvt_frag<<<(tot + 255) / 256, 256, 0, stream>>>(wk, qkvT, 384, 384, 24, 72, 24, tot);
  tcvt_frag<<<(tot + 255) / 256, 256, 0, stream>>>(wv, qkvT, 384, 384, 24, 72, 48, tot);
  tcvt_frag<<<(tot + 255) / 256, 256, 0, stream>>>(wo, woT, 384, 384, 24, 24, 0, tot);
  tot = 6 * 384 * 1536;
  tcvt_frag<<<(tot + 255) / 256, 256, 0, stream>>>(w1, w1T, 384, 1536, 96, 96, 0, tot);
  tcvt_frag<<<(tot + 255) / 256, 256, 0, stream>>>(w2, w2T, 1536, 384, 24, 24, 0, tot);
  tot = 384 * 128;
  tcvt_frag<<<(tot + 255) / 256, 256, 0, stream>>>(head_w, hdT, 384, 95, 8, 8, 0, tot);

  embed_kernel<<<(Mn * 96) / 256, 256, 0, stream>>>(idx, tok_emb, pos_emb, x);
  ln_kernel<<<Mn / 4, 256, 0, stream>>>(x, ln1_s, ln1_b, h);   // layer-0 LN1

  for (int l = 0; l < 6; l++) {
    gemm_h<4, false, 6, 72><<<2304, 256, 0, stream>>>(h, qkvT + l * 442368, nullptr, nullptr, qb);
    attn_kernel<<<Bn * Hn * 4, 256, 0, stream>>>(qb, kb, vb, ab);
    // WO + residual + LN2 fused -> x, h
    gemm_ln<6><<<256, 512, 0, stream>>>(ab, woT + l * 147456, bo + l * Dn, x, x,
                                        ln2_s + l * Dn, ln2_b + l * Dn, h);
    // FFN1+relu+FFN2 + residual + LN1(next)/LNF fused -> x, h  (f1 eliminated)
    const float* ns = (l < 5) ? (ln1_s + (l + 1) * Dn) : lnf_s;
    const float* nb = (l < 5) ? (ln1_b + (l + 1) * Dn) : lnf_b;
    ffn_ln<<<256, 512, 0, stream>>>(h, w1T + l * 589824, b1 + l * FFn,
                                    w2T + l * 589824, b2 + l * Dn,
                                    x, x, ns, nb, h);
  }
  gemm_h<3, false, 6, 8><<<256, 256, 0, stream>>>(h, hdT, head_b, nullptr, out);
}

// Round 13
// 1451.346 us; speedup vs baseline: 1.5154x; 1.0368x over previous
//
#include <hip/hip_runtime.h>
#include <hip/hip_bf16.h>
#include <cstdint>

#define DEV __device__ __forceinline__

typedef __hip_bfloat16 bf16;
typedef unsigned short u16;
typedef unsigned int u32;
typedef __attribute__((ext_vector_type(8))) short s8v;   // 8 bf16 (4 VGPRs) MFMA A/B frag
typedef __attribute__((ext_vector_type(4))) float f4;    // MFMA C/D frag

static constexpr int Bn = 128;
static constexpr int Tn = 256;
static constexpr int Dn = 384;
static constexpr int Hn = 6;
static constexpr int HDn = 64;
static constexpr int FFn = 1536;
static constexpr int Vn = 95;
static constexpr int Mn = Bn * 256;   // 32768

DEV u16 f2b(float f) {
  bf16 h = __float2bfloat16(f);
  return *reinterpret_cast<u16*>(&h);
}
DEV u32 pk2(float a, float b) { return (u32)f2b(a) | ((u32)f2b(b) << 16); }

// async 16B global->LDS. LDS destination is wave-uniform base + lane*16.
DEV void gl_lds16(const void* g, void* l) {
  auto gp = (const __attribute__((address_space(1))) u32*)(uintptr_t)g;
  auto lp = (__attribute__((address_space(3))) u32*)(u32)(uintptr_t)l;
  __builtin_amdgcn_global_load_lds(gp, lp, 16, 0, 0);
}

// counted vmcnt with literal immediate (folds under full unroll)
DEV void waitvm(int n) {
  if (n == 0)       asm volatile("s_waitcnt vmcnt(0)" ::: "memory");
  else if (n == 2)  asm volatile("s_waitcnt vmcnt(2)" ::: "memory");
  else if (n == 4)  asm volatile("s_waitcnt vmcnt(4)" ::: "memory");
  else if (n == 6)  asm volatile("s_waitcnt vmcnt(6)" ::: "memory");
  else if (n == 8)  asm volatile("s_waitcnt vmcnt(8)" ::: "memory");
  else if (n == 12) asm volatile("s_waitcnt vmcnt(12)" ::: "memory");
  else              asm volatile("s_waitcnt vmcnt(16)" ::: "memory");
}

// ---------------------------------------------------------------------------
// Hybrid GEMM — R4 single-barrier pipelined schedule (QKV / head).
// MODE 0: bf16 out [M,N]   MODE 3: f32 head out [M,95] col-guarded
// MODE 4: fused QKV: n<384 q; n<768 k; n>=768 v in vT layout [(b,h)][d][t]
// ---------------------------------------------------------------------------
template <int MODE, bool RELU, int NKT, int NT>
__global__ __launch_bounds__(256, 2) void gemm_h(
    const u16* __restrict__ A, const u16* __restrict__ Bw,
    const float* __restrict__ bias, const float* __restrict__ resid,
    void* __restrict__ outp)
{
  constexpr int K = NKT * 64;
  constexpr int N = NT * 16;
  constexpr int nTiles = NT / 8;
  __shared__ __align__(16) u16 As[3][128 * 64];
  const int tid = threadIdx.x;
  const int lane = tid & 63, wave = tid >> 6;
  const int quad = lane >> 4, l16 = lane & 15;
  const int wy = wave >> 1, wx = wave & 1;
  const int blk = blockIdx.x;
  const int xcd = blk & 7, tt = blk >> 3;
  const int nT = tt % nTiles, mT = xcd + 8 * (tt / nTiles);
  const int mBase = mT * 128, nBase = nT * 128;

  f4 acc[4][4] = {};

  int rS[4], cS[4];
#pragma unroll
  for (int i = 0; i < 4; i++) {
    int s = i * 256 + tid;
    rS[i] = s >> 3;
    cS[i] = ((s & 7) ^ (rS[i] & 7)) * 8;
  }

  const u16* Ab = A + (size_t)mBase * K;
  const u16* Bp = Bw + (size_t)((nBase >> 4) + wx * 4) * 512 + lane * 8;

#define STAGEA(buf, kt)                                                       \
  do {                                                                        \
    _Pragma("unroll")                                                         \
    for (int i = 0; i < 4; i++)                                               \
      gl_lds16(Ab + (size_t)rS[i] * K + (kt) + cS[i],                         \
               &As[buf][(i * 256 + wave * 64) * 8]);                          \
  } while (0)

  // prologue: issue order MUST be stage(0), bqa(0), stage(1)
  s8v bqa[2][4];
  STAGEA(0, 0);
  __builtin_amdgcn_sched_barrier(0);
#pragma unroll
  for (int j = 0; j < 4; j++)
    bqa[0][j] = *(const s8v*)(Bp + (size_t)0 * (NT * 512) + j * 512);
  __builtin_amdgcn_sched_barrier(0);
  STAGEA(1, 64);
  __builtin_amdgcn_sched_barrier(0);

  const int nk = NKT;
#pragma unroll
  for (int ik = 0; ik < nk; ik++) {
    const int cur = ik % 3;
    const int par = ik & 1;
    waitvm((ik + 1 < nk) ? 4 : 0);
    asm volatile("s_barrier" ::: "memory");
    s8v bqb[4];
#pragma unroll
    for (int j = 0; j < 4; j++)
      bqb[j] = *(const s8v*)(Bp + (size_t)(ik * 2 + 1) * (NT * 512) + j * 512);
    __builtin_amdgcn_sched_barrier(0);
    if (ik + 1 < nk) {
#pragma unroll
      for (int j = 0; j < 4; j++)
        bqa[par ^ 1][j] = *(const s8v*)(Bp + (size_t)(ik * 2 + 2) * (NT * 512) + j * 512);
    }
    __builtin_amdgcn_sched_barrier(0);
    if (ik + 2 < nk) STAGEA((ik + 2) % 3, (ik + 2) * 64);
    __builtin_amdgcn_sched_barrier(0);
    {
      s8v af[4];
#pragma unroll
      for (int i = 0; i < 4; i++) {
        int row = wy * 64 + i * 16 + l16;
        int ch = quad ^ (row & 7);
        af[i] = *(const s8v*)&As[cur][row * 64 + ch * 8];
      }
#pragma unroll
      for (int i = 0; i < 4; i++)
#pragma unroll
        for (int j = 0; j < 4; j++)
          acc[i][j] = __builtin_amdgcn_mfma_f32_16x16x32_bf16(af[i], bqa[par][j], acc[i][j], 0, 0, 0);
    }
    waitvm(4 * ((ik + 1 < nk) + (ik + 2 < nk)));
    {
      s8v af[4];
#pragma unroll
      for (int i = 0; i < 4; i++) {
        int row = wy * 64 + i * 16 + l16;
        int ch = (4 + quad) ^ (row & 7);
        af[i] = *(const s8v*)&As[cur][row * 64 + ch * 8];
      }
#pragma unroll
      for (int i = 0; i < 4; i++)
#pragma unroll
        for (int j = 0; j < 4; j++)
          acc[i][j] = __builtin_amdgcn_mfma_f32_16x16x32_bf16(af[i], bqb[j], acc[i][j], 0, 0, 0);
    }
  }
#undef STAGEA

  if (MODE == 0) {
    u16* out = (u16*)outp;
#pragma unroll
    for (int j = 0; j < 4; j++) {
      int n = nBase + wx * 64 + j * 16 + l16;
      float bv = bias ? bias[n] : 0.f;
#pragma unroll
      for (int i = 0; i < 4; i++) {
        int m0 = mBase + wy * 64 + i * 16 + quad * 4;
#pragma unroll
        for (int r = 0; r < 4; r++) {
          float v = acc[i][j][r] + bv;
          if (RELU) v = fmaxf(v, 0.f);
          out[(size_t)(m0 + r) * N + n] = f2b(v);
        }
      }
    }
  } else if (MODE == 3) {
    float* out = (float*)outp;
#pragma unroll
    for (int j = 0; j < 4; j++) {
      int n = nBase + wx * 64 + j * 16 + l16;
      if (n < Vn) {
        float bv = bias[n];
#pragma unroll
        for (int i = 0; i < 4; i++) {
          int m0 = mBase + wy * 64 + i * 16 + quad * 4;
#pragma unroll
          for (int r = 0; r < 4; r++)
            out[(size_t)(m0 + r) * Vn + n] = acc[i][j][r] + bv;
        }
      }
    }
  } else if (MODE == 4) {
    u16* qb = (u16*)outp;
    u16* kb = qb + (size_t)Mn * 384;
    u16* vb = kb + (size_t)Mn * 384;
#pragma unroll
    for (int j = 0; j < 4; j++) {
      int n = nBase + wx * 64 + j * 16 + l16;
      if (n < 768) {
        u16* dst = (n < 384) ? qb : kb;
        int col = (n < 384) ? n : (n - 384);   // 384 is NOT pow2 — no mask!
#pragma unroll
        for (int i = 0; i < 4; i++) {
          int m0 = mBase + wy * 64 + i * 16 + quad * 4;
#pragma unroll
          for (int r = 0; r < 4; r++)
            dst[(size_t)(m0 + r) * 384 + col] = f2b(acc[i][j][r]);
        }
      } else {
        int n7 = n - 768;
        int hh = n7 >> 6, d = n7 & 63;
#pragma unroll
        for (int i = 0; i < 4; i++) {
          int m0 = mBase + wy * 64 + i * 16 + quad * 4;
          int b = m0 >> 8, t0 = m0 & 255;
          uint2 w;
          w.x = pk2(acc[i][j][0], acc[i][j][1]);
          w.y = pk2(acc[i][j][2], acc[i][j][3]);
          *(uint2*)&vb[((b * Hn + hh) * HDn + d) * Tn + t0] = w;
        }
      }
    }
  }
}

// ---------------------------------------------------------------------------
// WO GEMM + residual-add + LayerNorm fusion (N=384 full-row tile), R6 form.
// At the mixed-rw traffic ceiling (~61us = 170MB / 2.8 TB/s) — unchanged.
// ---------------------------------------------------------------------------
template <int NKT>
__global__ __launch_bounds__(512, 2) void gemm_ln(
    const u16* __restrict__ A, const u16* __restrict__ Bw,
    const float* __restrict__ bias, const float* __restrict__ resid,
    float* __restrict__ xout,
    const float* __restrict__ sc, const float* __restrict__ bi,
    u16* __restrict__ hout)
{
  constexpr int K = NKT * 64;
  constexpr int NT = 24;               // 384 / 16
  __shared__ __align__(16) u16 As[2][128 * 64];
  __shared__ __align__(16) u16 Bs[2][24576];      // 2 ks x 24 nt x 512
  __shared__ float2 red[4][128];
  const int tid = threadIdx.x;
  const int lane = tid & 63, wave = tid >> 6;       // 0..7
  const int quad = lane >> 4, l16 = lane & 15;
  const int wy = wave >> 2, wx = wave & 3;          // 2 x 4
  const int blk = blockIdx.x;
  const int mT = (blk & 7) + 8 * (blk >> 3);        // XCD-major
  const int mBase = mT * 128;

  f4 acc[4][6] = {};

  int rS[2], cS[2];
#pragma unroll
  for (int i = 0; i < 2; i++) {
    int s = i * 512 + tid;
    rS[i] = s >> 3;
    cS[i] = ((s & 7) ^ (rS[i] & 7)) * 8;
  }

  const u16* Ab = A + (size_t)mBase * K;

#define STAGEL(buf, kt)                                                       \
  do {                                                                        \
    _Pragma("unroll")                                                         \
    for (int i = 0; i < 2; i++)                                               \
      gl_lds16(Ab + (size_t)rS[i] * K + (kt) + cS[i],                         \
               &As[buf][(i * 512 + wave * 64) * 8]);                          \
  } while (0)

#define STAGEB2(buf, ikk)                                                     \
  do {                                                                        \
    _Pragma("unroll")                                                         \
    for (int L = 0; L < 6; L++) {                                             \
      int ks = L / 3, th = L % 3;                                             \
      int c = th * 4096 + tid * 8;                                            \
      gl_lds16(Bw + (size_t)((ikk) * 2 + ks) * (NT * 512) + c,                \
               &Bs[buf][ks * 12288 + c]);                                     \
    }                                                                         \
  } while (0)

  STAGEL(0, 0);
  STAGEB2(0, 0);

  const int nk = NKT;
#pragma unroll
  for (int ik = 0; ik < nk; ik++) {
    const int cur = ik & 1;
    asm volatile("s_waitcnt vmcnt(0)" ::: "memory");
    asm volatile("s_barrier" ::: "memory");
    if (ik + 1 < nk) {
      STAGEL(cur ^ 1, (ik + 1) * 64);
      STAGEB2(cur ^ 1, ik + 1);
    }
    __builtin_amdgcn_sched_barrier(0);
#pragma unroll
    for (int ks = 0; ks < 2; ks++) {
      s8v af[4], bq[6];
#pragma unroll
      for (int i = 0; i < 4; i++) {
        int row = wy * 64 + i * 16 + l16;
        int ch = (ks * 4 + quad) ^ (row & 7);
        af[i] = *(const s8v*)&As[cur][row * 64 + ch * 8];
      }
#pragma unroll
      for (int j = 0; j < 6; j++)
        bq[j] = *(const s8v*)&Bs[cur][ks * 12288 + (wx * 6 + j) * 512 + lane * 8];
#pragma unroll
      for (int i = 0; i < 4; i++)
#pragma unroll
        for (int j = 0; j < 6; j++)
          acc[i][j] = __builtin_amdgcn_mfma_f32_16x16x32_bf16(af[i], bq[j], acc[i][j], 0, 0, 0);
    }
  }
#undef STAGEL
#undef STAGEB2

  // ---- epilogue: x = resid + C + bias; row stats; h = LN(x)*sc + bi ----
  f4 psum[4] = {}, psq[4] = {};
#pragma unroll
  for (int j = 0; j < 6; j++) {
    int n = wx * 96 + j * 16 + l16;
    float bv = bias[n];
#pragma unroll
    for (int i = 0; i < 4; i++) {
      int m0 = mBase + wy * 64 + i * 16 + quad * 4;
#pragma unroll
      for (int r = 0; r < 4; r++) {
        int m = m0 + r;
        float v = resid[(size_t)m * Dn + n] + acc[i][j][r] + bv;
        xout[(size_t)m * Dn + n] = v;
        acc[i][j][r] = v;
        psum[i][r] += v;
        psq[i][r] += v * v;
      }
    }
  }
#pragma unroll
  for (int o = 1; o < 16; o <<= 1)
#pragma unroll
    for (int i = 0; i < 4; i++)
#pragma unroll
      for (int r = 0; r < 4; r++) {
        psum[i][r] += __shfl_xor(psum[i][r], o);
        psq[i][r] += __shfl_xor(psq[i][r], o);
      }
  if (l16 == 0) {
#pragma unroll
    for (int i = 0; i < 4; i++)
#pragma unroll
      for (int r = 0; r < 4; r++) {
        int lr = wy * 64 + i * 16 + quad * 4 + r;
        float2 p; p.x = psum[i][r]; p.y = psq[i][r];
        red[wx][lr] = p;
      }
  }
  __syncthreads();
  float scv[6], biv[6];
#pragma unroll
  for (int j = 0; j < 6; j++) {
    int n = wx * 96 + j * 16 + l16;
    scv[j] = sc[n];
    biv[j] = bi[n];
  }
#pragma unroll
  for (int i = 0; i < 4; i++)
#pragma unroll
    for (int r = 0; r < 4; r++) {
      int lr = wy * 64 + i * 16 + quad * 4 + r;
      float ts = 0.f, tq = 0.f;
#pragma unroll
      for (int w = 0; w < 4; w++) { float2 p = red[w][lr]; ts += p.x; tq += p.y; }
      float mean = ts * (1.f / 384.f);
      float inv = rsqrtf(tq * (1.f / 384.f) - mean * mean + 1e-5f);
      int m = mBase + lr;
#pragma unroll
      for (int j = 0; j < 6; j++) {
        int n = wx * 96 + j * 16 + l16;
        hout[(size_t)m * Dn + n] = f2b((acc[i][j][r] - mean) * inv * scv[j] + biv[j]);
      }
    }
}

// ---------------------------------------------------------------------------
// R13: FUSED FFN — R7's EXACT 2-barrier structure (verified 103us / total
// 1457.6), with ONE variable changed: Hs stored as 6 As-style [128][64]
// subtiles (R11-verified addressing, conflicts 7.08M->2.36M).
// R12 post-mortem: the merged 1-barrier seg-loop was the regression (140us
// with FEWER conflicts than R7's 103us) — conflict count and time are
// decoupled; the 2-phase structure schedules better. This round isolates
// whether the conflict reduction is worth anything on the good base.
// LDS: Hs 96K + Ps 32K + red 4K = 132KB, 1 block/CU. Everything else
// byte-identical to R7's ffn_ln.
// ---------------------------------------------------------------------------
__global__ __launch_bounds__(512, 2) void ffn_ln(
    const u16* __restrict__ A, const u16* __restrict__ B1w,
    const float* __restrict__ b1, const u16* __restrict__ B2w,
    const float* __restrict__ b2, const float* __restrict__ resid,
    float* __restrict__ xout,
    const float* __restrict__ sc, const float* __restrict__ bi,
    u16* __restrict__ hout)
{
  __shared__ __align__(16) u16 Hs[6 * 128 * 64];  // 96 KB, 6 subtiles
  __shared__ __align__(16) u16 Ps[128 * 128];     // 32 KB
  __shared__ float2 red[4][128];
  const int tid = threadIdx.x;
  const int lane = tid & 63, wave = tid >> 6;
  const int quad = lane >> 4, l16 = lane & 15;
  const int wy = wave >> 2, wx = wave & 3;
  const int mT = (blockIdx.x & 7) + 8 * (blockIdx.x >> 3);
  const int mBase = mT * 128;
  char* Psb = (char*)Ps;

  // ---- stage Hs as subtiles (R11-verified): slot S: ik=S>>10,
  // row=(S&1023)>>3, chunk-slot c=S&7 holds source chunk c^(row&7). ----
  {
    const u16* hg = A + (size_t)mBase * Dn;
#pragma unroll
    for (int i = 0; i < 12; i++) {
      u32 S = i * 512 + tid;
      u32 ik = S >> 10, s_in = S & 1023;
      u32 row = s_in >> 3, c = s_in & 7;
      u32 src = ik * 64 + (c ^ (row & 7)) * 8;
      gl_lds16(hg + (size_t)row * Dn + src, &Hs[S * 8]);
    }
  }
  asm volatile("s_waitcnt vmcnt(0)" ::: "memory");
  asm volatile("s_barrier" ::: "memory");

  f4 acc2[4][6] = {};
  const u16* B1p = B1w + (size_t)(wx * 2) * 512 + lane * 8;
  const u16* B2p = B2w + (size_t)(wx * 6) * 512 + lane * 8;
  s8v bq2[2][6];

#pragma unroll 1
  for (int c = 0; c < 12; c++) {
    // ---------------- GEMM1: P = relu(h @ W1[:,c*128..] + b1) -------------
    float4 b1v0 = *(const float4*)&b1[c * 128 + wx * 32 + quad * 4];
    float4 b1v1 = *(const float4*)&b1[c * 128 + wx * 32 + 16 + quad * 4];
    __builtin_amdgcn_sched_barrier(0);
    s8v bq1[2][4];
#pragma unroll
    for (int u = 0; u < 4; u++) {
      int ks = u >> 1, j = u & 1;
      bq1[0][u] = *(const s8v*)(B1p + (size_t)(ks * 96 + c * 8 + j) * 512);
    }
    __builtin_amdgcn_sched_barrier(0);
    f4 acc1[4][2] = {};
#pragma unroll
    for (int ik = 0; ik < 6; ik++) {
      const int par = ik & 1;
      if (ik + 1 < 6) {
#pragma unroll
        for (int u = 0; u < 4; u++) {
          int ks = u >> 1, j = u & 1;
          bq1[par ^ 1][u] = *(const s8v*)(B1p + (size_t)(((ik + 1) * 2 + ks) * 96 + c * 8 + j) * 512);
        }
      }
      __builtin_amdgcn_sched_barrier(0);
      waitvm((ik + 1 < 6) ? 4 : 0);   // retire bq1[par] (+b1 at ik=0)
#pragma unroll
      for (int ks = 0; ks < 2; ks++) {
        s8v af[4];
#pragma unroll
        for (int i = 0; i < 4; i++) {
          int row = wy * 64 + i * 16 + l16;
          int chx = (ks * 4 + quad) ^ (row & 7);
          af[i] = *(const s8v*)&Hs[ik * 8192 + row * 64 + chx * 8];
        }
#pragma unroll
        for (int i = 0; i < 4; i++)
#pragma unroll
          for (int j = 0; j < 2; j++)
            acc1[i][j] = __builtin_amdgcn_mfma_f32_16x16x32_bf16(
                bq1[par][ks * 2 + j], af[i], acc1[i][j], 0, 0, 0);
      }
    }
    // prefetch bq2 ks2=0 (independent of Ps) before the barrier
#pragma unroll
    for (int j = 0; j < 6; j++)
      bq2[0][j] = *(const s8v*)(B2p + (size_t)((c * 4) * 24 + j) * 512);
    __builtin_amdgcn_sched_barrier(0);
    // ---- P write: bias + relu + pack; swizzled uint2 stores ----
#pragma unroll
    for (int i = 0; i < 4; i++) {
      int m = wy * 64 + i * 16 + l16;
#pragma unroll
      for (int j = 0; j < 2; j++) {
        float4 bv4 = (j == 0) ? b1v0 : b1v1;
        float v0 = fmaxf(acc1[i][j][0] + bv4.x, 0.f);
        float v1 = fmaxf(acc1[i][j][1] + bv4.y, 0.f);
        float v2 = fmaxf(acc1[i][j][2] + bv4.z, 0.f);
        float v3 = fmaxf(acc1[i][j][3] + bv4.w, 0.f);
        uint2 w; w.x = pk2(v0, v1); w.y = pk2(v2, v3);
        int byteoff = (m * 256 + (wx * 32 + j * 16 + quad * 4) * 2) ^ ((m & 7) << 4);
        *(uint2*)(Psb + byteoff) = w;
      }
    }
    asm volatile("s_waitcnt lgkmcnt(0)" ::: "memory");
    asm volatile("s_barrier" ::: "memory");
    // ---------------- GEMM2: acc2 += P @ W2[c*128.., :] -------------------
#pragma unroll
    for (int ks2 = 0; ks2 < 4; ks2++) {
      const int p2 = ks2 & 1;
      if (ks2 + 1 < 4) {
#pragma unroll
        for (int j = 0; j < 6; j++)
          bq2[p2 ^ 1][j] = *(const s8v*)(B2p + (size_t)((c * 4 + ks2 + 1) * 24 + j) * 512);
      }
      __builtin_amdgcn_sched_barrier(0);
      waitvm((ks2 + 1 < 4) ? 6 : 0);
      s8v af2[4];
#pragma unroll
      for (int i = 0; i < 4; i++) {
        int m = wy * 64 + i * 16 + l16;
        int byteoff = (m * 256 + (ks2 * 4 + quad) * 16) ^ ((m & 7) << 4);
        af2[i] = *(const s8v*)(Psb + byteoff);
      }
#pragma unroll
      for (int i = 0; i < 4; i++)
#pragma unroll
        for (int j = 0; j < 6; j++)
          acc2[i][j] = __builtin_amdgcn_mfma_f32_16x16x32_bf16(
              af2[i], bq2[p2][j], acc2[i][j], 0, 0, 0);
    }
    asm volatile("s_waitcnt lgkmcnt(0)" ::: "memory");
    asm volatile("s_barrier" ::: "memory");   // WAR: Ps free for next chunk
  }

  // ---- epilogue: x = resid + acc2 + b2; row stats; h' = LN(x)*sc+bi ----
  f4 psum[4] = {}, psq[4] = {};
#pragma unroll
  for (int j = 0; j < 6; j++) {
    int n = wx * 96 + j * 16 + l16;
    float bv = b2[n];
#pragma unroll
    for (int i = 0; i < 4; i++) {
      int m0 = mBase + wy * 64 + i * 16 + quad * 4;
#pragma unroll
      for (int r = 0; r < 4; r++) {
        int m = m0 + r;
        float v = resid[(size_t)m * Dn + n] + acc2[i][j][r] + bv;
        xout[(size_t)m * Dn + n] = v;
        acc2[i][j][r] = v;
        psum[i][r] += v;
        psq[i][r] += v * v;
      }
    }
  }
#pragma unroll
  for (int o = 1; o < 16; o <<= 1)
#pragma unroll
    for (int i = 0; i < 4; i++)
#pragma unroll
      for (int r = 0; r < 4; r++) {
        psum[i][r] += __shfl_xor(psum[i][r], o);
        psq[i][r] += __shfl_xor(psq[i][r], o);
      }
  if (l16 == 0) {
#pragma unroll
    for (int i = 0; i < 4; i++)
#pragma unroll
      for (int r = 0; r < 4; r++) {
        int lr = wy * 64 + i * 16 + quad * 4 + r;
        float2 p; p.x = psum[i][r]; p.y = psq[i][r];
        red[wx][lr] = p;
      }
  }
  __syncthreads();
  float scv[6], biv[6];
#pragma unroll
  for (int j = 0; j < 6; j++) {
    int n = wx * 96 + j * 16 + l16;
    scv[j] = sc[n];
    biv[j] = bi[n];
  }
#pragma unroll
  for (int i = 0; i < 4; i++)
#pragma unroll
    for (int r = 0; r < 4; r++) {
      int lr = wy * 64 + i * 16 + quad * 4 + r;
      float ts = 0.f, tq = 0.f;
#pragma unroll
      for (int w = 0; w < 4; w++) { float2 p = red[w][lr]; ts += p.x; tq += p.y; }
      float mean = ts * (1.f / 384.f);
      float inv = rsqrtf(tq * (1.f / 384.f) - mean * mean + 1e-5f);
      int m = mBase + lr;
#pragma unroll
      for (int j = 0; j < 6; j++) {
        int n = wx * 96 + j * 16 + l16;
        hout[(size_t)m * Dn + n] = f2b((acc2[i][j][r] - mean) * inv * scv[j] + biv[j]);
      }
    }
}

// ---------------------------------------------------------------------------
// Flash-chunked attention v2 (unchanged).
// ---------------------------------------------------------------------------
__global__ __launch_bounds__(256) void attn_kernel(
    const u16* __restrict__ q, const u16* __restrict__ k,
    const u16* __restrict__ vT, u16* __restrict__ ao)
{
  __shared__ __align__(16) u16 Psh[4][2][16 * 40];
  const int tid = threadIdx.x, lane = tid & 63, wave = tid >> 6;
  const int quad = lane >> 4, l16 = lane & 15;
  const int c4 = blockIdx.x / 768;
  const int bh = blockIdx.x - c4 * 768;
  const int b = bh / Hn, h = bh % Hn;
  const u16* qg = q + (b * Tn) * Dn + h * HDn;
  const u16* kg = k + (b * Tn) * Dn + h * HDn;
  const u16* vg = vT + bh * (HDn * Tn);
  u16* aog = ao + (b * Tn) * Dn + h * HDn;
  const float c1 = 0.125f * 1.44269504f;  // scale * log2(e)

  const int qt = (wave & 2) ? ((wave & 1) ? 15 - c4 : 8 + c4)
                            : ((wave & 1) ? 7 - c4 : c4);
  const int qglob = qt * 16 + l16;

  const s8v qf0 = *(const s8v*)&qg[qglob * Dn + quad * 8];
  const s8v qf1 = *(const s8v*)&qg[qglob * Dn + 32 + quad * 8];

  float lsum = 0.f;
  f4 O[4] = {};

  const int nch = qt / 2 + 1;
  for (int c2 = 0; c2 < nch; c2++) {
    const int kk0 = c2 * 32;
    f4 S0 = {0.f, 0.f, 0.f, 0.f}, S1 = S0;
    {
      s8v kf = *(const s8v*)&kg[(kk0 + l16) * Dn + quad * 8];
      S0 = __builtin_amdgcn_mfma_f32_16x16x32_bf16(kf, qf0, S0, 0, 0, 0);
      kf = *(const s8v*)&kg[(kk0 + l16) * Dn + 32 + quad * 8];
      S0 = __builtin_amdgcn_mfma_f32_16x16x32_bf16(kf, qf1, S0, 0, 0, 0);
    }
    if (kk0 + 16 <= qt * 16) {
      s8v kf = *(const s8v*)&kg[(kk0 + 16 + l16) * Dn + quad * 8];
      S1 = __builtin_amdgcn_mfma_f32_16x16x32_bf16(kf, qf0, S1, 0, 0, 0);
      kf = *(const s8v*)&kg[(kk0 + 16 + l16) * Dn + 32 + quad * 8];
      S1 = __builtin_amdgcn_mfma_f32_16x16x32_bf16(kf, qf1, S1, 0, 0, 0);
    }
    const int kkq = kk0 + quad * 4;
    f4 E0, E1;
#pragma unroll
    for (int r = 0; r < 4; r++) {
      E0[r] = (kkq + r <= qglob) ? exp2f(S0[r] * c1) : 0.f;
      E1[r] = (kkq + 16 + r <= qglob) ? exp2f(S1[r] * c1) : 0.f;
      lsum += E0[r] + E1[r];
    }
    u16* prow = &Psh[wave][c2 & 1][l16 * 40];
    uint2 w0, w1;
    w0.x = pk2(E0[0], E0[1]); w0.y = pk2(E0[2], E0[3]);
    w1.x = pk2(E1[0], E1[1]); w1.y = pk2(E1[2], E1[3]);
    *(uint2*)&prow[quad * 4] = w0;
    *(uint2*)&prow[16 + quad * 4] = w1;
    const s8v pf = *(const s8v*)&prow[quad * 8];
#pragma unroll
    for (int dm = 0; dm < 4; dm++) {
      s8v vf = *(const s8v*)&vg[(dm * 16 + l16) * Tn + kk0 + quad * 8];
      O[dm] = __builtin_amdgcn_mfma_f32_16x16x32_bf16(vf, pf, O[dm], 0, 0, 0);
    }
  }

  lsum += __shfl_xor(lsum, 16);
  lsum += __shfl_xor(lsum, 32);
  const float inv = 1.0f / lsum;
#pragma unroll
  for (int dm = 0; dm < 4; dm++) {
    uint2 w;
    w.x = pk2(O[dm][0] * inv, O[dm][1] * inv);
    w.y = pk2(O[dm][2] * inv, O[dm][3] * inv);
    *(uint2*)&aog[qglob * Dn + dm * 16 + quad * 4] = w;
  }
}

// ---------------------------------------------------------------------------
// LayerNorm: one wave per token — used ONCE (after embed, layer-0 LN1).
// ---------------------------------------------------------------------------
__global__ __launch_bounds__(256) void ln_kernel(
    const float* __restrict__ x, const float* __restrict__ sc,
    const float* __restrict__ bi, u16* __restrict__ out)
{
  int tok = blockIdx.x * 4 + (threadIdx.x >> 6);
  int lane = threadIdx.x & 63;
  const float* xr = x + (size_t)tok * Dn;
  float v[6];
  float s = 0.f, sq = 0.f;
#pragma unroll
  for (int i = 0; i < 6; i++) {
    v[i] = xr[lane + 64 * i];
    s += v[i];
    sq += v[i] * v[i];
  }
#pragma unroll
  for (int o = 1; o < 64; o <<= 1) {
    s += __shfl_xor(s, o);
    sq += __shfl_xor(sq, o);
  }
  float mean = s * (1.f / 384.f);
  float var = sq * (1.f / 384.f) - mean * mean;
  float inv = rsqrtf(var + 1e-5f);
  u16* orow = out + (size_t)tok * Dn;
#pragma unroll
  for (int i = 0; i < 6; i++) {
    int c = lane + 64 * i;
    orow[c] = f2b((v[i] - mean) * inv * sc[c] + bi[c]);
  }
}

// x[m][:] = tok_emb[idx[m]][:] + pos_emb[m%T][:]  (float4 per thread)
__global__ __launch_bounds__(256) void embed_kernel(
    const int* __restrict__ idx, const float* __restrict__ tok,
    const float* __restrict__ pos, float* __restrict__ x)
{
  int i = blockIdx.x * 256 + threadIdx.x;  // [0, M*96)
  int m = i / 96, c = (i - m * 96) * 4;
  int t = m & (Tn - 1);
  const float4 tv = *(const float4*)&tok[idx[m] * Dn + c];
  const float4 pv = *(const float4*)&pos[t * Dn + c];
  float4 r;
  r.x = tv.x + pv.x; r.y = tv.y + pv.y; r.z = tv.z + pv.z; r.w = tv.w + pv.w;
  *(float4*)&x[m * Dn + c] = r;
}

// ---------------------------------------------------------------------------
// Weight converter -> MFMA B-fragment order.
// dst[((l*KC + kc)*NTtot + ntoff + nt)*512 + lane*8 + j8] = w[l][k][n] (bf16)
//   where k = kc*32 + (lane>>4)*8 + j8, n = nt*16 + (lane&15), zero if n >= C.
// ---------------------------------------------------------------------------
__global__ __launch_bounds__(256) void tcvt_frag(
    const float* __restrict__ src, u16* __restrict__ dst,
    int K, int C, int NTsub, int NTtot, int ntoff, int total)
{
  int t = blockIdx.x * 256 + threadIdx.x;
  if (t >= total) return;
  int j8 = t & 7;
  int lane = (t >> 3) & 63;
  int rest = t >> 9;
  int nt = rest % NTsub;
  int lkc = rest / NTsub;
  int KC = K >> 5;
  int kc = lkc % KC;
  int l = lkc / KC;
  int quad = lane >> 4, l16 = lane & 15;
  int k = kc * 32 + quad * 8 + j8;
  int n = nt * 16 + l16;
  float v = (n < C) ? src[((size_t)l * K + k) * C + n] : 0.f;
  dst[((size_t)(l * KC + kc) * NTtot + ntoff + nt) * 512 + lane * 8 + j8] = f2b(v);
}

extern "C" void kernel_launch(void* const* d_in, const int* in_sizes, int n_in,
                              void* d_out, int out_size, void* d_ws, size_t ws_size,
                              hipStream_t stream)
{
  (void)in_sizes; (void)n_in; (void)out_size;
  const int*   idx     = (const int*)d_in[0];
  const float* tok_emb = (const float*)d_in[1];
  const float* pos_emb = (const float*)d_in[2];
  const float* ln1_s   = (const float*)d_in[3];
  const float* ln1_b   = (const float*)d_in[4];
  const float* wq      = (const float*)d_in[5];
  const float* wk      = (const float*)d_in[6];
  const float* wv      = (const float*)d_in[7];
  const float* wo      = (const float*)d_in[8];
  const float* bo      = (const float*)d_in[9];
  const float* ln2_s   = (const float*)d_in[10];
  const float* ln2_b   = (const float*)d_in[11];
  const float* w1      = (const float*)d_in[12];
  const float* b1      = (const float*)d_in[13];
  const float* w2      = (const float*)d_in[14];
  const float* b2      = (const float*)d_in[15];
  const float* lnf_s   = (const float*)d_in[16];
  const float* lnf_b   = (const float*)d_in[17];
  const float* head_w  = (const float*)d_in[18];
  const float* head_b  = (const float*)d_in[19];
  float* out = (float*)d_out;

  // workspace layout (bytes)
  char* ws = (char*)d_ws;
  float* x  = (float*)(ws + 0);             // 50,331,648  fp32 residual stream
  u16*   h  = (u16*)(ws + 50331648);        // 25,165,824  LN output (bf16)
  u16*   qb = (u16*)(ws + 75497472);        // 25,165,824  (q,k,v contiguous!)
  u16*   kb = (u16*)(ws + 100663296);       // 25,165,824
  u16*   vb = (u16*)(ws + 125829120);       // 25,165,824  V^T [(b,h)][d][t]
  u16*   ab = (u16*)(ws + 150994944);       // 25,165,824  attn out
  u16* qkvT = (u16*)(ws + 176160768);       // 6 * 442368 (frag layout, NTtot=72)
  u16* woT  = qkvT + 6 * 442368;            // 6 * 147456 (NTtot=24)
  u16* w1T  = woT + 6 * 147456;             // 6 * 589824 (NTtot=96, K=384)
  u16* w2T  = w1T + 6 * 589824;             // 6 * 589824 (NTtot=24, K=1536)
  u16* hdT  = w2T + 6 * 589824;             // 49152 (NTtot=8, 95->128 pad)
  if (ws_size < (size_t)197492736) return;

  int tot = 6 * 384 * 384;
  tcvt_frag<<<(tot + 255) / 256, 256, 0, stream>>>(wq, qkvT, 384, 384, 24, 72, 0, tot);
  tcvt_frag<<<(tot + 255) / 256, 256, 0, stream>>>(wk, qkvT, 384, 384, 24, 72, 24, tot);
  tcvt_frag<<<(tot + 255) / 256, 256, 0, stream>>>(wv, qkvT, 384, 384, 24, 72, 48, tot);
  tcvt_frag<<<(tot + 255) / 256, 256, 0, stream>>>(wo, woT, 384, 384, 24, 24, 0, tot);
  tot = 6 * 384 * 1536;
  tcvt_frag<<<(tot + 255) / 256, 256, 0, stream>>>(w1, w1T, 384, 1536, 96, 96, 0, tot);
  tcvt_frag<<<(tot + 255) / 256, 256, 0, stream>>>(w2, w2T, 1536, 384, 24, 24, 0, tot);
  tot = 384 * 128;
  tcvt_frag<<<(tot + 255) / 256, 256, 0, stream>>>(head_w, hdT, 384, 95, 8, 8, 0, tot);

  embed_kernel<<<(Mn * 96) / 256, 256, 0, stream>>>(idx, tok_emb, pos_emb, x);
  ln_kernel<<<Mn / 4, 256, 0, stream>>>(x, ln1_s, ln1_b, h);   // layer-0 LN1

  for (int l = 0; l < 6; l++) {
    gemm_h<4, false, 6, 72><<<2304, 256, 0, stream>>>(h, qkvT + l * 442368, nullptr, nullptr, qb);
    attn_kernel<<<Bn * Hn * 4, 256, 0, stream>>>(qb, kb, vb, ab);
    // WO + residual + LN2 fused -> x, h
    gemm_ln<6><<<256, 512, 0, stream>>>(ab, woT + l * 147456, bo + l * Dn, x, x,
                                        ln2_s + l * Dn, ln2_b + l * Dn, h);
    // FFN1+relu+FFN2 + residual + LN1(next)/LNF fused -> x, h  (f1 eliminated)
    const float* ns = (l < 5) ? (ln1_s + (l + 1) * Dn) : lnf_s;
    const float* nb = (l < 5) ? (ln1_b + (l + 1) * Dn) : lnf_b;
    ffn_ln<<<256, 512, 0, stream>>>(h, w1T + l * 589824, b1 + l * FFn,
                                    w2T + l * 589824, b2 + l * Dn,
                                    x, x, ns, nb, h);
  }
  gemm_h<3, false, 6, 8><<<256, 256, 0, stream>>>(h, hdT, head_b, nullptr, out);
}